// Round 2
// baseline (699.926 us; speedup 1.0000x reference)
//
#include <hip/hip_runtime.h>
#include <hip/hip_bf16.h>
#include <hip/hip_cooperative_groups.h>
#include <math.h>

namespace cg = cooperative_groups;

#define BSZ 4
#define SEQ 1024
#define DIM 768
#define NH 12
#define NEnt 42
#define MM 8
#define PPairs 500
#define INC 3
#define OUTC 256
#define EMB 768
#define BLKsz 64
#define NL 97
#define NPAIR (BSZ*PPairs)   // 2000
#define XROWS 2048
#define NCHUNK 24

typedef __bf16 bf16x8 __attribute__((ext_vector_type(8)));
typedef __bf16 bf16x4 __attribute__((ext_vector_type(4)));
typedef float f32x4 __attribute__((ext_vector_type(4)));

// ---- workspace byte offsets ----
#define OFF_EEMB  4096
#define OFF_EATT  520192
#define OFF_SP    4648960
#define OFF_XB    4698112
#define OFF_WHT   13086720
#define OFF_WT    16232448
#define OFF_HSB   25767936
#define OFF_TSB   28839936
#define OFF_PART  31911936

// stage1 virtual-block ranges
#define B_EEMB0 0
#define B_EATT0 168
#define B_SP0   2184
#define B_WHT0  3208
#define B_WT0   3592
#define B_ZERO0 4360
#define B_TOTAL 4362

__device__ __forceinline__ float ldin(const void* p, long long i, int f32) {
  if (f32) return ((const float*)p)[i];
  unsigned int u = (unsigned int)(((const unsigned short*)p)[i]) << 16;
  union { unsigned int u; float f; } c; c.u = u;
  return c.f;
}

__device__ __forceinline__ f32x4 ldin4(const void* p, long long i, int f32) {
  f32x4 r;
  if (f32) {
    r = *(const f32x4*)((const float*)p + i);
  } else {
    unsigned long long v = *(const unsigned long long*)((const unsigned short*)p + i);
    union { unsigned int u; float f; } c;
    c.u = (unsigned int)(v & 0xFFFFu) << 16;         r[0] = c.f;
    c.u = (unsigned int)((v >> 16) & 0xFFFFu) << 16; r[1] = c.f;
    c.u = (unsigned int)((v >> 32) & 0xFFFFu) << 16; r[2] = c.f;
    c.u = (unsigned int)((v >> 48) & 0xFFFFu) << 16; r[3] = c.f;
  }
  return r;
}

__device__ __forceinline__ float tanhf_fast(float x) {
  float ax = fabsf(x);
  float t = __expf(-2.0f*ax);
  float r = (1.0f - t)/(1.0f + t);
  return x < 0.0f ? -r : r;
}

struct MegaParams {
  const void* seq; const void* att; const int* etok; const void* emask;
  const int* hts; const void* wliner; const void* bliner; const void* wseg;
  const void* bseg; const void* whead; const void* bhead; const void* wtail;
  const void* btail; const void* wbil; const void* bbil; void* out;
  float* e_emb; __bf16* e_att; float* sp; __bf16* Xb; __bf16* whT; __bf16* wT;
  __bf16* hsb; __bf16* tsb; _Float16* part24;
};

// ============================ mega kernel =============================
__global__ __launch_bounds__(256)
void k_mega(MegaParams P) {
  __shared__ __align__(16) char smem_raw[36864];
  __shared__ int sflag;
  const int tid = threadIdx.x;
  const int nb = gridDim.x;
  const int w = tid >> 6, lane = tid & 63, quad = lane >> 4, col = lane & 15;

  // ---- inline dtype detect (per block, cheap) ----
  if (tid < 64) {
    unsigned int word = ((const unsigned int*)P.whead)[tid];
    union { unsigned int u; float f; } c; c.u = (word & 0xFFFFu) << 16;
    unsigned long long m = __ballot(fabsf(c.f) > 1.0f);
    if (tid == 0) sflag = (__popcll(m) >= 8) ? 1 : 0;
  }
  __syncthreads();
  const int f32 = sflag;

  cg::grid_group grid = cg::this_grid();
  float* smemf = (float*)smem_raw;

  // ================= P0: stage1 (e_emb, e_att, sp, whT, wT, zeropad) ======
  for (int blk = blockIdx.x; blk < B_TOTAL; blk += nb) {
    __syncthreads();   // protect smem reuse across virtual blocks
    if (blk < B_EATT0) {
      int be = blk, b = be / NEnt;
      int* sidx = (int*)smemf;
      float* sval = smemf + 16;
      if (tid < MM) {
        int t = P.etok[be*MM + tid];
        int ip = t + 1;
        float v = ldin(P.emask, be*MM + tid, f32);
        sval[tid] = (ip < SEQ) ? v : 0.0f;
        sidx[tid] = ip < 0 ? 0 : (ip > SEQ-1 ? SEQ-1 : ip);
      }
      __syncthreads();
      float cnt = 0.0f;
#pragma unroll
      for (int m = 0; m < MM; m++) cnt += sval[m];
      for (int d = tid; d < DIM; d += 256) {
        float x[MM];
#pragma unroll
        for (int m = 0; m < MM; m++)
          x[m] = ldin(P.seq, ((long long)(b*SEQ) + sidx[m])*DIM + d, f32);
        float mx = -1e30f;
#pragma unroll
        for (int m = 0; m < MM; m++) if (sval[m] > 0.0f && x[m] > mx) mx = x[m];
        float s = 0.0f;
#pragma unroll
        for (int m = 0; m < MM; m++) if (sval[m] > 0.0f) s += expf(x[m] - mx);
        P.e_emb[(long long)be*DIM + d] = (cnt > 0.0f) ? (mx + logf(s)) : 0.0f;
      }
    } else if (blk < B_SP0) {
      int t1 = blk - B_EATT0;
      int h = t1 % NH, be = t1 / NH, b = be / NEnt;
      int* sidx = (int*)smemf;
      float* sval = smemf + 16;
      if (tid < MM) {
        int t = P.etok[be*MM + tid];
        int ip = t + 1;
        float v = ldin(P.emask, be*MM + tid, f32);
        sval[tid] = (ip < SEQ) ? v : 0.0f;
        sidx[tid] = ip < 0 ? 0 : (ip > SEQ-1 ? SEQ-1 : ip);
      }
      __syncthreads();
      float cnt = 0.0f;
#pragma unroll
      for (int m = 0; m < MM; m++) cnt += sval[m];
      float rs = (cnt > 0.0f) ? 1.0f/fmaxf(cnt, 1.0f) : 0.0f;
      long long abase = ((long long)(b*NH + h))*SEQ*SEQ;
      int s0 = tid*4;
      f32x4 acc = (f32x4){0,0,0,0};
#pragma unroll
      for (int m = 0; m < MM; m++)
        if (sval[m] > 0.0f) {
          f32x4 v = ldin4(P.att, abase + (long long)sidx[m]*SEQ + s0, f32);
          acc += sval[m]*v;
        }
      bf16x4 ov;
#pragma unroll
      for (int k = 0; k < 4; k++) ov[k] = (__bf16)(acc[k]*rs);
      *(bf16x4*)(P.e_att + ((long long)(be*NH + h))*SEQ + s0) = ov;
    } else if (blk < B_WHT0) {
      int t2 = blk - B_SP0;            // 0..1023
      int b = t2 >> 8;
      int wv = tid >> 6, l = tid & 63;
      int s = ((t2 & 255) << 2) + wv;
      long long rb = ((long long)(b*SEQ) + s)*DIM;
      float a0 = 0, a1 = 0, a2 = 0;
#pragma unroll
      for (int i = 0; i < DIM/64; i++) {
        int d = l + i*64;
        float x = ldin(P.seq, rb + d, f32);
        a0 += x*ldin(P.wliner, (long long)d*3 + 0, f32);
        a1 += x*ldin(P.wliner, (long long)d*3 + 1, f32);
        a2 += x*ldin(P.wliner, (long long)d*3 + 2, f32);
      }
#pragma unroll
      for (int o = 32; o; o >>= 1) {
        a0 += __shfl_down(a0, o);
        a1 += __shfl_down(a1, o);
        a2 += __shfl_down(a2, o);
      }
      if (l == 0) {
        P.sp[0*(BSZ*SEQ) + b*SEQ + s] = a0;
        P.sp[1*(BSZ*SEQ) + b*SEQ + s] = a1;
        P.sp[2*(BSZ*SEQ) + b*SEQ + s] = a2;
      }
    } else if (blk < B_WT0) {
      int t3 = blk - B_WHT0;           // 0..383
      int kb = t3 & 15, rest = t3 >> 4;
      int nbk = rest % 12, y = rest / 12;
      const void* W = y ? P.wtail : P.whead;
      for (int i = tid; i < 64*64; i += 256) {
        int r = i >> 6, c = i & 63;
        smemf[r*65 + c] = ldin(W, (long long)(kb*64 + r)*EMB + nbk*64 + c, f32);
      }
      __syncthreads();
      for (int j = tid; j < 64*64; j += 256) {
        int r = j >> 6, k = j & 63;
        P.whT[((long long)y*EMB + nbk*64 + r)*1024 + kb*64 + k] = (__bf16)smemf[k*65 + r];
      }
    } else if (blk < B_ZERO0) {
      int t4 = blk - B_WT0;            // 0..767
      int kb = t4 & 63, g = t4 >> 6;
      long long base = ((long long)g*4096 + kb*64)*97;
      for (int i = tid; i < 64*97; i += 256)
        smemf[(i/97)*98 + (i%97)] = ldin(P.wbil, base + i, f32);
      __syncthreads();
      for (int j = tid; j < 97*64; j += 256) {
        int l = j >> 6, k = j & 63;
        P.wT[((long long)g*97 + l)*4096 + kb*64 + k] = (__bf16)smemf[k*98 + l];
      }
    } else {
      int y = blk - B_ZERO0;
      uint4 z = {0,0,0,0};
      uint4* dst = (uint4*)(P.Xb + ((long long)(y*XROWS + NPAIR))*1024);
      for (int i = tid; i < 48*1024*2/16; i += 256) dst[i] = z;
    }
  }
  grid.sync();

  // ================= P1: per-pair pooling + seg + X build =================
  float (*cross)[4] = (float (*)[4])smem_raw;
  for (int p = blockIdx.x; p < NPAIR; p += nb) {
    __syncthreads();
    int b = p / PPairs;
    int hi = P.hts[p*2 + 0];
    int ti = P.hts[p*2 + 1];
    const __bf16* ei = P.e_att + ((long long)(b*NEnt + hi))*NH*SEQ;
    const __bf16* ej = P.e_att + ((long long)(b*NEnt + ti))*NH*SEQ;
    int s0 = tid*4;
    f32x4 q = (f32x4){0,0,0,0};
#pragma unroll
    for (int h = 0; h < NH; h++) {
      bf16x4 xi = *(const bf16x4*)(ei + h*SEQ + s0);
      bf16x4 xj = *(const bf16x4*)(ej + h*SEQ + s0);
#pragma unroll
      for (int k = 0; k < 4; k++) q[k] += (float)xi[k]*(float)xj[k];
    }
    f32x4 w0 = *(const f32x4*)(P.sp + 0*(BSZ*SEQ) + b*SEQ + s0);
    f32x4 w1 = *(const f32x4*)(P.sp + 1*(BSZ*SEQ) + b*SEQ + s0);
    f32x4 w2 = *(const f32x4*)(P.sp + 2*(BSZ*SEQ) + b*SEQ + s0);
    float dn = q[0]+q[1]+q[2]+q[3];
    float a0 = q[0]*w0[0]+q[1]*w0[1]+q[2]*w0[2]+q[3]*w0[3];
    float a1 = q[0]*w1[0]+q[1]*w1[1]+q[2]*w1[2]+q[3]*w1[3];
    float a2 = q[0]*w2[0]+q[1]*w2[1]+q[2]*w2[2]+q[3]*w2[3];
#pragma unroll
    for (int o = 32; o; o >>= 1) {
      dn += __shfl_down(dn, o);
      a0 += __shfl_down(a0, o);
      a1 += __shfl_down(a1, o);
      a2 += __shfl_down(a2, o);
    }
    if (lane == 0) { cross[0][w] = dn; cross[1][w] = a0; cross[2][w] = a1; cross[3][w] = a2; }
    __syncthreads();
    float DN = cross[0][0]+cross[0][1]+cross[0][2]+cross[0][3];
    float A0 = cross[1][0]+cross[1][1]+cross[1][2]+cross[1][3];
    float A1 = cross[2][0]+cross[2][1]+cross[2][2]+cross[2][3];
    float A2 = cross[3][0]+cross[3][1]+cross[3][2]+cross[3][3];
    const float inv = 1.0f/(float)NH;
    float scale = inv/(DN*inv + 1e-5f);
    float v0 = A0*scale + ldin(P.bliner, 0, f32);
    float v1 = A1*scale + ldin(P.bliner, 1, f32);
    float v2 = A2*scale + ldin(P.bliner, 2, f32);
    float o = ldin(P.bseg, tid, f32)
            + v0*ldin(P.wseg, 0*OUTC + tid, f32)
            + v1*ldin(P.wseg, 1*OUTC + tid, f32)
            + v2*ldin(P.wseg, 2*OUTC + tid, f32);
    __bf16* X0 = P.Xb + ((long long)(0*XROWS + p))*1024;
    __bf16* X1 = P.Xb + ((long long)(1*XROWS + p))*1024;
    X0[DIM + tid] = (__bf16)o;
    X1[DIM + tid] = (__bf16)o;
    const float* eh = P.e_emb + (long long)(b*NEnt + hi)*DIM;
    const float* et = P.e_emb + (long long)(b*NEnt + ti)*DIM;
    for (int k = tid; k < DIM; k += 256) {
      X0[k] = (__bf16)eh[k];
      X1[k] = (__bf16)et[k];
    }
  }
  grid.sync();

  // ================= P2: head/tail GEMM + tanh (64-row units) =============
  for (int u = blockIdx.x; u < 32*12*2; u += nb) {
    __syncthreads();
    int m0 = (u & 31) << 6;
    int rest = u >> 5;
    int n0 = (rest % 12) << 6;
    int y  = rest / 12;
    __bf16 (*Xa)[64][72] = (__bf16 (*)[64][72])smem_raw;
    __bf16 (*Bb)[64][72] = (__bf16 (*)[64][72])(smem_raw + 18432);
    const __bf16* Xg = P.Xb + (long long)y*XROWS*1024;
    const __bf16* Wg = P.whT + ((long long)y*EMB + n0)*1024;
    auto stage = [&](int kk, int pb) {
#pragma unroll
      for (int it = 0; it < 2; it++) {
        int r = (tid >> 3) + (it << 5);
        int c0 = (tid & 7) << 3;
        *(bf16x8*)&Xa[pb][r][c0] = *(const bf16x8*)(Xg + (long long)(m0 + r)*1024 + kk + c0);
        *(bf16x8*)&Bb[pb][r][c0] = *(const bf16x8*)(Wg + (long long)r*1024 + kk + c0);
      }
    };
    f32x4 acc[4];
#pragma unroll
    for (int nt = 0; nt < 4; nt++) acc[nt] = (f32x4){0,0,0,0};
    stage(0, 0);
    __syncthreads();
    for (int c = 0; c < 16; c++) {
      int pb = c & 1;
      if (c + 1 < 16) stage((c+1)*64, pb ^ 1);
#pragma unroll
      for (int s = 0; s < 2; s++) {
        bf16x8 av = *(bf16x8*)&Xa[pb][(w<<4) + col][s*32 + quad*8];
        bf16x8 bv[4];
#pragma unroll
        for (int nt = 0; nt < 4; nt++)
          bv[nt] = *(bf16x8*)&Bb[pb][nt*16 + col][s*32 + quad*8];
#pragma unroll
        for (int nt = 0; nt < 4; nt++)
          acc[nt] = __builtin_amdgcn_mfma_f32_16x16x32_bf16(av, bv[nt], acc[nt], 0, 0, 0);
      }
      __syncthreads();
    }
    const void* Bv = y ? P.btail : P.bhead;
    __bf16* outp = y ? P.tsb : P.hsb;
#pragma unroll
    for (int nt = 0; nt < 4; nt++) {
      int n = n0 + nt*16 + col;
      float bias = ldin(Bv, n, f32);
#pragma unroll
      for (int reg = 0; reg < 4; reg++) {
        int m = m0 + (w<<4) + quad*4 + reg;
        if (m < NPAIR)
          outp[(long long)m*EMB + n] = (__bf16)tanhf_fast(acc[nt][reg] + bias);
      }
    }
  }
  grid.sync();

  // ================= P3: bilinear MFMA (64-row x chunk units) =============
  for (int u = blockIdx.x; u < 32*NCHUNK; u += nb) {
    __syncthreads();
    int m0 = (u & 31) << 6;
    int c  = u >> 5;
    int g = c >> 1, kh = c & 1;
    __bf16 (*hslT)[72] = (__bf16 (*)[72])smem_raw;   // [32][72]
    {
      int srow = tid & 63;
      int grow = m0 + srow; if (grow > NPAIR-1) grow = NPAIR-1;
      int ah = (tid >> 6) << 3;
      const __bf16* hp = P.hsb + (long long)grow*EMB + g*BLKsz + kh*32 + ah;
      bf16x8 hv8 = *(const bf16x8*)hp;
#pragma unroll
      for (int j = 0; j < 8; j++) hslT[ah + j][srow] = hv8[j];
    }
    bf16x8 tsv[2];
    {
      int row = m0 + (w<<4) + col; if (row > NPAIR-1) row = NPAIR-1;
      const __bf16* tp = P.tsb + (long long)row*EMB + g*BLKsz + quad*8;
      tsv[0] = *(const bf16x8*)(tp);
      tsv[1] = *(const bf16x8*)(tp + 32);
    }
    __syncthreads();
    const __bf16* wg = P.wT + (long long)g*NL*4096 + kh*2048 + quad*8;
    int boff[7];
#pragma unroll
    for (int nt = 0; nt < 7; nt++) {
      int l = nt*16 + col; if (l > 96) l = 96;
      boff[nt] = l*4096;
    }
    f32x4 acc[7];
#pragma unroll
    for (int nt = 0; nt < 7; nt++) acc[nt] = (f32x4){0,0,0,0};
    bf16x8 bv[2][7];
#pragma unroll
    for (int nt = 0; nt < 7; nt++) bv[0][nt] = *(const bf16x8*)(wg + boff[nt]);
#pragma unroll
    for (int nt = 0; nt < 7; nt++) bv[1][nt] = *(const bf16x8*)(wg + boff[nt] + 32);
    for (int a = 0; a < 32; a++) {
      float hv = (float)hslT[a][(w<<4) + col];
#pragma unroll
      for (int half = 0; half < 2; half++) {
        bf16x8 af;
#pragma unroll
        for (int j = 0; j < 8; j++) af[j] = (__bf16)(hv * (float)tsv[half][j]);
#pragma unroll
        for (int nt = 0; nt < 7; nt++)
          acc[nt] = __builtin_amdgcn_mfma_f32_16x16x32_bf16(af, bv[half][nt], acc[nt], 0, 0, 0);
        int knext = (a+1)*64 + half*32;
        if (knext >= 2048) knext = a*64 + half*32;  // harmless refill at tail
#pragma unroll
        for (int nt = 0; nt < 7; nt++)
          bv[half][nt] = *(const bf16x8*)(wg + boff[nt] + knext);
      }
    }
    _Float16* ps = P.part24 + (long long)c*NPAIR*NL;
#pragma unroll
    for (int nt = 0; nt < 7; nt++)
#pragma unroll
      for (int reg = 0; reg < 4; reg++) {
        int n = m0 + (w<<4) + quad*4 + reg;
        int l = nt*16 + col;
        if (n < NPAIR && l < NL)
          ps[(long long)n*NL + l] = (_Float16)acc[nt][reg];
      }
  }
  grid.sync();

  // ================= P4: final reduction ==================================
  for (int i = blockIdx.x*256 + tid; i < NPAIR*NL; i += nb*256) {
    int l = i % NL;
    float v = ldin(P.bbil, l, f32);
#pragma unroll
    for (int c = 0; c < NCHUNK; c++) v += (float)P.part24[(long long)c*NPAIR*NL + i];
    if (f32) ((float*)P.out)[i] = v;
    else ((__hip_bfloat16*)P.out)[i] = __float2bfloat16(v);
  }
}

// ===================== fallback (non-cooperative) path =====================
__global__ void k_detect(const void* w_head, int* flag) {
  int tid = threadIdx.x;
  unsigned int word = ((const unsigned int*)w_head)[tid];
  union { unsigned int u; float f; } c;
  c.u = (word & 0xFFFFu) << 16;
  unsigned long long m = __ballot(fabsf(c.f) > 1.0f);
  if (tid == 0) flag[0] = (__popcll(m) >= 8) ? 1 : 0;
}

__global__ __launch_bounds__(256)
void k_fb(MegaParams P, const int* flag, int phase) {
  // crude fallback: re-run mega phases as separate launches using flag buffer
  // phase: 0=stage1, 1=pair, 2=htmm, 3=bil, 4=final
  __shared__ __align__(16) char smem_raw[36864];
  const int tid = threadIdx.x;
  const int f32 = *flag;
  const int w = tid >> 6, lane = tid & 63, quad = lane >> 4, col = lane & 15;
  float* smemf = (float*)smem_raw;
  if (phase == 0) {
    int blk = blockIdx.x;
    if (blk < B_EATT0) {
      int be = blk, b = be / NEnt;
      int* sidx = (int*)smemf; float* sval = smemf + 16;
      if (tid < MM) {
        int t = P.etok[be*MM + tid]; int ip = t + 1;
        float v = ldin(P.emask, be*MM + tid, f32);
        sval[tid] = (ip < SEQ) ? v : 0.0f;
        sidx[tid] = ip < 0 ? 0 : (ip > SEQ-1 ? SEQ-1 : ip);
      }
      __syncthreads();
      float cnt = 0.0f;
#pragma unroll
      for (int m = 0; m < MM; m++) cnt += sval[m];
      for (int d = tid; d < DIM; d += 256) {
        float x[MM];
#pragma unroll
        for (int m = 0; m < MM; m++)
          x[m] = ldin(P.seq, ((long long)(b*SEQ) + sidx[m])*DIM + d, f32);
        float mx = -1e30f;
#pragma unroll
        for (int m = 0; m < MM; m++) if (sval[m] > 0.0f && x[m] > mx) mx = x[m];
        float s = 0.0f;
#pragma unroll
        for (int m = 0; m < MM; m++) if (sval[m] > 0.0f) s += expf(x[m] - mx);
        P.e_emb[(long long)be*DIM + d] = (cnt > 0.0f) ? (mx + logf(s)) : 0.0f;
      }
    } else if (blk < B_SP0) {
      int t1 = blk - B_EATT0;
      int h = t1 % NH, be = t1 / NH, b = be / NEnt;
      int* sidx = (int*)smemf; float* sval = smemf + 16;
      if (tid < MM) {
        int t = P.etok[be*MM + tid]; int ip = t + 1;
        float v = ldin(P.emask, be*MM + tid, f32);
        sval[tid] = (ip < SEQ) ? v : 0.0f;
        sidx[tid] = ip < 0 ? 0 : (ip > SEQ-1 ? SEQ-1 : ip);
      }
      __syncthreads();
      float cnt = 0.0f;
#pragma unroll
      for (int m = 0; m < MM; m++) cnt += sval[m];
      float rs = (cnt > 0.0f) ? 1.0f/fmaxf(cnt, 1.0f) : 0.0f;
      long long abase = ((long long)(b*NH + h))*SEQ*SEQ;
      int s0 = tid*4;
      f32x4 acc = (f32x4){0,0,0,0};
#pragma unroll
      for (int m = 0; m < MM; m++)
        if (sval[m] > 0.0f) acc += sval[m]*ldin4(P.att, abase + (long long)sidx[m]*SEQ + s0, f32);
      bf16x4 ov;
#pragma unroll
      for (int k = 0; k < 4; k++) ov[k] = (__bf16)(acc[k]*rs);
      *(bf16x4*)(P.e_att + ((long long)(be*NH + h))*SEQ + s0) = ov;
    } else if (blk < B_WHT0) {
      int t2 = blk - B_SP0; int b = t2 >> 8;
      int wv = tid >> 6, l = tid & 63;
      int s = ((t2 & 255) << 2) + wv;
      long long rb = ((long long)(b*SEQ) + s)*DIM;
      float a0 = 0, a1 = 0, a2 = 0;
#pragma unroll
      for (int i = 0; i < DIM/64; i++) {
        int d = l + i*64;
        float x = ldin(P.seq, rb + d, f32);
        a0 += x*ldin(P.wliner, (long long)d*3 + 0, f32);
        a1 += x*ldin(P.wliner, (long long)d*3 + 1, f32);
        a2 += x*ldin(P.wliner, (long long)d*3 + 2, f32);
      }
#pragma unroll
      for (int o = 32; o; o >>= 1) {
        a0 += __shfl_down(a0, o); a1 += __shfl_down(a1, o); a2 += __shfl_down(a2, o);
      }
      if (l == 0) {
        P.sp[0*(BSZ*SEQ) + b*SEQ + s] = a0;
        P.sp[1*(BSZ*SEQ) + b*SEQ + s] = a1;
        P.sp[2*(BSZ*SEQ) + b*SEQ + s] = a2;
      }
    } else if (blk < B_WT0) {
      int t3 = blk - B_WHT0;
      int kb = t3 & 15, rest = t3 >> 4;
      int nbk = rest % 12, y = rest / 12;
      const void* W = y ? P.wtail : P.whead;
      for (int i = tid; i < 64*64; i += 256) {
        int r = i >> 6, c = i & 63;
        smemf[r*65 + c] = ldin(W, (long long)(kb*64 + r)*EMB + nbk*64 + c, f32);
      }
      __syncthreads();
      for (int j = tid; j < 64*64; j += 256) {
        int r = j >> 6, k = j & 63;
        P.whT[((long long)y*EMB + nbk*64 + r)*1024 + kb*64 + k] = (__bf16)smemf[k*65 + r];
      }
    } else if (blk < B_ZERO0) {
      int t4 = blk - B_WT0;
      int kb = t4 & 63, g = t4 >> 6;
      long long base = ((long long)g*4096 + kb*64)*97;
      for (int i = tid; i < 64*97; i += 256)
        smemf[(i/97)*98 + (i%97)] = ldin(P.wbil, base + i, f32);
      __syncthreads();
      for (int j = tid; j < 97*64; j += 256) {
        int l = j >> 6, k = j & 63;
        P.wT[((long long)g*97 + l)*4096 + kb*64 + k] = (__bf16)smemf[k*98 + l];
      }
    } else {
      int y = blk - B_ZERO0;
      uint4 z = {0,0,0,0};
      uint4* dst = (uint4*)(P.Xb + ((long long)(y*XROWS + NPAIR))*1024);
      for (int i = tid; i < 48*1024*2/16; i += 256) dst[i] = z;
    }
  } else if (phase == 1) {
    float (*cross)[4] = (float (*)[4])smem_raw;
    int p = blockIdx.x;
    int b = p / PPairs;
    int hi = P.hts[p*2 + 0], ti = P.hts[p*2 + 1];
    const __bf16* ei = P.e_att + ((long long)(b*NEnt + hi))*NH*SEQ;
    const __bf16* ej = P.e_att + ((long long)(b*NEnt + ti))*NH*SEQ;
    int s0 = tid*4;
    f32x4 q = (f32x4){0,0,0,0};
#pragma unroll
    for (int h = 0; h < NH; h++) {
      bf16x4 xi = *(const bf16x4*)(ei + h*SEQ + s0);
      bf16x4 xj = *(const bf16x4*)(ej + h*SEQ + s0);
#pragma unroll
      for (int k = 0; k < 4; k++) q[k] += (float)xi[k]*(float)xj[k];
    }
    f32x4 w0 = *(const f32x4*)(P.sp + 0*(BSZ*SEQ) + b*SEQ + s0);
    f32x4 w1 = *(const f32x4*)(P.sp + 1*(BSZ*SEQ) + b*SEQ + s0);
    f32x4 w2 = *(const f32x4*)(P.sp + 2*(BSZ*SEQ) + b*SEQ + s0);
    float dn = q[0]+q[1]+q[2]+q[3];
    float a0 = q[0]*w0[0]+q[1]*w0[1]+q[2]*w0[2]+q[3]*w0[3];
    float a1 = q[0]*w1[0]+q[1]*w1[1]+q[2]*w1[2]+q[3]*w1[3];
    float a2 = q[0]*w2[0]+q[1]*w2[1]+q[2]*w2[2]+q[3]*w2[3];
#pragma unroll
    for (int o = 32; o; o >>= 1) {
      dn += __shfl_down(dn, o); a0 += __shfl_down(a0, o);
      a1 += __shfl_down(a1, o); a2 += __shfl_down(a2, o);
    }
    if (lane == 0) { cross[0][w] = dn; cross[1][w] = a0; cross[2][w] = a1; cross[3][w] = a2; }
    __syncthreads();
    float DN = cross[0][0]+cross[0][1]+cross[0][2]+cross[0][3];
    float A0 = cross[1][0]+cross[1][1]+cross[1][2]+cross[1][3];
    float A1 = cross[2][0]+cross[2][1]+cross[2][2]+cross[2][3];
    float A2 = cross[3][0]+cross[3][1]+cross[3][2]+cross[3][3];
    const float inv = 1.0f/(float)NH;
    float scale = inv/(DN*inv + 1e-5f);
    float v0 = A0*scale + ldin(P.bliner, 0, f32);
    float v1 = A1*scale + ldin(P.bliner, 1, f32);
    float v2 = A2*scale + ldin(P.bliner, 2, f32);
    float o = ldin(P.bseg, tid, f32)
            + v0*ldin(P.wseg, 0*OUTC + tid, f32)
            + v1*ldin(P.wseg, 1*OUTC + tid, f32)
            + v2*ldin(P.wseg, 2*OUTC + tid, f32);
    __bf16* X0 = P.Xb + ((long long)(0*XROWS + p))*1024;
    __bf16* X1 = P.Xb + ((long long)(1*XROWS + p))*1024;
    X0[DIM + tid] = (__bf16)o; X1[DIM + tid] = (__bf16)o;
    const float* eh = P.e_emb + (long long)(b*NEnt + hi)*DIM;
    const float* et = P.e_emb + (long long)(b*NEnt + ti)*DIM;
    for (int k = tid; k < DIM; k += 256) { X0[k] = (__bf16)eh[k]; X1[k] = (__bf16)et[k]; }
  } else if (phase == 2) {
    int u = blockIdx.x;
    int m0 = (u & 31) << 6;
    int rest = u >> 5;
    int n0 = (rest % 12) << 6;
    int y  = rest / 12;
    __bf16 (*Xa)[64][72] = (__bf16 (*)[64][72])smem_raw;
    __bf16 (*Bb)[64][72] = (__bf16 (*)[64][72])(smem_raw + 18432);
    const __bf16* Xg = P.Xb + (long long)y*XROWS*1024;
    const __bf16* Wg = P.whT + ((long long)y*EMB + n0)*1024;
    auto stage = [&](int kk, int pb) {
#pragma unroll
      for (int it = 0; it < 2; it++) {
        int r = (tid >> 3) + (it << 5);
        int c0 = (tid & 7) << 3;
        *(bf16x8*)&Xa[pb][r][c0] = *(const bf16x8*)(Xg + (long long)(m0 + r)*1024 + kk + c0);
        *(bf16x8*)&Bb[pb][r][c0] = *(const bf16x8*)(Wg + (long long)r*1024 + kk + c0);
      }
    };
    f32x4 acc[4];
#pragma unroll
    for (int nt = 0; nt < 4; nt++) acc[nt] = (f32x4){0,0,0,0};
    stage(0, 0);
    __syncthreads();
    for (int c = 0; c < 16; c++) {
      int pb = c & 1;
      if (c + 1 < 16) stage((c+1)*64, pb ^ 1);
#pragma unroll
      for (int s = 0; s < 2; s++) {
        bf16x8 av = *(bf16x8*)&Xa[pb][(w<<4) + col][s*32 + quad*8];
        bf16x8 bvv[4];
#pragma unroll
        for (int nt = 0; nt < 4; nt++) bvv[nt] = *(bf16x8*)&Bb[pb][nt*16 + col][s*32 + quad*8];
#pragma unroll
        for (int nt = 0; nt < 4; nt++)
          acc[nt] = __builtin_amdgcn_mfma_f32_16x16x32_bf16(av, bvv[nt], acc[nt], 0, 0, 0);
      }
      __syncthreads();
    }
    const void* Bv = y ? P.btail : P.bhead;
    __bf16* outp = y ? P.tsb : P.hsb;
#pragma unroll
    for (int nt = 0; nt < 4; nt++) {
      int n = n0 + nt*16 + col;
      float bias = ldin(Bv, n, f32);
#pragma unroll
      for (int reg = 0; reg < 4; reg++) {
        int m = m0 + (w<<4) + quad*4 + reg;
        if (m < NPAIR) outp[(long long)m*EMB + n] = (__bf16)tanhf_fast(acc[nt][reg] + bias);
      }
    }
  } else if (phase == 3) {
    int u = blockIdx.x;
    int m0 = (u & 31) << 6;
    int c  = u >> 5;
    int g = c >> 1, kh = c & 1;
    __bf16 (*hslT)[72] = (__bf16 (*)[72])smem_raw;
    {
      int srow = tid & 63;
      int grow = m0 + srow; if (grow > NPAIR-1) grow = NPAIR-1;
      int ah = (tid >> 6) << 3;
      const __bf16* hp = P.hsb + (long long)grow*EMB + g*BLKsz + kh*32 + ah;
      bf16x8 hv8 = *(const bf16x8*)hp;
#pragma unroll
      for (int j = 0; j < 8; j++) hslT[ah + j][srow] = hv8[j];
    }
    bf16x8 tsv[2];
    {
      int row = m0 + (w<<4) + col; if (row > NPAIR-1) row = NPAIR-1;
      const __bf16* tp = P.tsb + (long long)row*EMB + g*BLKsz + quad*8;
      tsv[0] = *(const bf16x8*)(tp); tsv[1] = *(const bf16x8*)(tp + 32);
    }
    __syncthreads();
    const __bf16* wg = P.wT + (long long)g*NL*4096 + kh*2048 + quad*8;
    int boff[7];
#pragma unroll
    for (int nt = 0; nt < 7; nt++) { int l = nt*16 + col; if (l > 96) l = 96; boff[nt] = l*4096; }
    f32x4 acc[7];
#pragma unroll
    for (int nt = 0; nt < 7; nt++) acc[nt] = (f32x4){0,0,0,0};
    bf16x8 bv[2][7];
#pragma unroll
    for (int nt = 0; nt < 7; nt++) bv[0][nt] = *(const bf16x8*)(wg + boff[nt]);
#pragma unroll
    for (int nt = 0; nt < 7; nt++) bv[1][nt] = *(const bf16x8*)(wg + boff[nt] + 32);
    for (int a = 0; a < 32; a++) {
      float hv = (float)hslT[a][(w<<4) + col];
#pragma unroll
      for (int half = 0; half < 2; half++) {
        bf16x8 af;
#pragma unroll
        for (int j = 0; j < 8; j++) af[j] = (__bf16)(hv * (float)tsv[half][j]);
#pragma unroll
        for (int nt = 0; nt < 7; nt++)
          acc[nt] = __builtin_amdgcn_mfma_f32_16x16x32_bf16(af, bv[half][nt], acc[nt], 0, 0, 0);
        int knext = (a+1)*64 + half*32;
        if (knext >= 2048) knext = a*64 + half*32;
#pragma unroll
        for (int nt = 0; nt < 7; nt++) bv[half][nt] = *(const bf16x8*)(wg + boff[nt] + knext);
      }
    }
    _Float16* ps = P.part24 + (long long)c*NPAIR*NL;
#pragma unroll
    for (int nt = 0; nt < 7; nt++)
#pragma unroll
      for (int reg = 0; reg < 4; reg++) {
        int n = m0 + (w<<4) + quad*4 + reg;
        int l = nt*16 + col;
        if (n < NPAIR && l < NL) ps[(long long)n*NL + l] = (_Float16)acc[nt][reg];
      }
  } else {
    int i = blockIdx.x*256 + tid;
    if (i < NPAIR*NL) {
      int l = i % NL;
      float v = ldin(P.bbil, l, f32);
#pragma unroll
      for (int c = 0; c < NCHUNK; c++) v += (float)P.part24[(long long)c*NPAIR*NL + i];
      if (f32) ((float*)P.out)[i] = v;
      else ((__hip_bfloat16*)P.out)[i] = __float2bfloat16(v);
    }
  }
}

extern "C" void kernel_launch(void* const* d_in, const int* in_sizes, int n_in,
                              void* d_out, int out_size, void* d_ws, size_t ws_size,
                              hipStream_t stream) {
  char* ws = (char*)d_ws;
  MegaParams p;
  p.seq    = d_in[0];  p.att    = d_in[1];
  p.etok   = (const int*)d_in[2];
  p.emask  = d_in[3];
  p.hts    = (const int*)d_in[4];
  p.wliner = d_in[5];  p.bliner = d_in[6];
  p.wseg   = d_in[7];  p.bseg   = d_in[8];
  p.whead  = d_in[9];  p.bhead  = d_in[10];
  p.wtail  = d_in[11]; p.btail  = d_in[12];
  p.wbil   = d_in[13]; p.bbil   = d_in[14];
  p.out    = d_out;
  p.e_emb  = (float*)(ws + OFF_EEMB);
  p.e_att  = (__bf16*)(ws + OFF_EATT);
  p.sp     = (float*)(ws + OFF_SP);
  p.Xb     = (__bf16*)(ws + OFF_XB);
  p.whT    = (__bf16*)(ws + OFF_WHT);
  p.wT     = (__bf16*)(ws + OFF_WT);
  p.hsb    = (__bf16*)(ws + OFF_HSB);
  p.tsb    = (__bf16*)(ws + OFF_TSB);
  p.part24 = (_Float16*)(ws + OFF_PART);

  static int gblocks = -1;
  if (gblocks < 0) {
    int dev = 0; hipGetDevice(&dev);
    int ncu = 0;
    if (hipDeviceGetAttribute(&ncu, hipDeviceAttributeMultiprocessorCount, dev) != hipSuccess || ncu <= 0)
      ncu = 256;
    int occ = 0;
    if (hipOccupancyMaxActiveBlocksPerMultiprocessor(&occ, k_mega, 256, 0) != hipSuccess || occ <= 0)
      occ = 1;
    long long g = (long long)occ * (long long)ncu;
    if (g > B_TOTAL) g = B_TOTAL;
    if (g < 1) g = 1;
    gblocks = (int)g;
  }

  void* args[] = { (void*)&p };
  hipError_t err = hipLaunchCooperativeKernel((const void*)k_mega, dim3(gblocks), dim3(256),
                                              args, 0, stream);
  if (err != hipSuccess) {
    // fallback: classic multi-launch path
    int* flag = (int*)ws;
    k_detect<<<1, 64, 0, stream>>>(p.whead, flag);
    k_fb<<<B_TOTAL, 256, 0, stream>>>(p, flag, 0);
    k_fb<<<NPAIR, 256, 0, stream>>>(p, flag, 1);
    k_fb<<<32*12*2, 256, 0, stream>>>(p, flag, 2);
    k_fb<<<32*NCHUNK, 256, 0, stream>>>(p, flag, 3);
    k_fb<<<(NPAIR*NL + 255)/256, 256, 0, stream>>>(p, flag, 4);
  }
}

// Round 3
// 488.460 us; speedup vs baseline: 1.4329x; 1.4329x over previous
//
#include <hip/hip_runtime.h>
#include <hip/hip_bf16.h>
#include <hip/hip_cooperative_groups.h>
#include <math.h>

namespace cg = cooperative_groups;

#define BSZ 4
#define SEQ 1024
#define DIM 768
#define NH 12
#define NEnt 42
#define MM 8
#define PPairs 500
#define INC 3
#define OUTC 256
#define EMB 768
#define BLKsz 64
#define NL 97
#define NPAIR (BSZ*PPairs)   // 2000
#define XROWS 2048
#define NCHUNK 24

typedef __bf16 bf16x8 __attribute__((ext_vector_type(8)));
typedef __bf16 bf16x4 __attribute__((ext_vector_type(4)));
typedef float f32x4 __attribute__((ext_vector_type(4)));

// ---- workspace byte offsets ----
#define OFF_EEMB  4096
#define OFF_EATT  520192
#define OFF_SP    4648960
#define OFF_XB    4698112
#define OFF_WHT   13086720
#define OFF_WT    16232448
#define OFF_HSB   25767936
#define OFF_TSB   28839936
#define OFF_PART  31911936

// stage1 virtual-block ranges
#define B_EEMB0 0
#define B_EATT0 168
#define B_SP0   2184
#define B_WHT0  3208
#define B_WT0   3592
#define B_ZERO0 4360
#define B_TOTAL 4362

__device__ __forceinline__ float ldin(const void* p, long long i, int f32) {
  if (f32) return ((const float*)p)[i];
  unsigned int u = (unsigned int)(((const unsigned short*)p)[i]) << 16;
  union { unsigned int u; float f; } c; c.u = u;
  return c.f;
}

__device__ __forceinline__ f32x4 ldin4(const void* p, long long i, int f32) {
  f32x4 r;
  if (f32) {
    r = *(const f32x4*)((const float*)p + i);
  } else {
    unsigned long long v = *(const unsigned long long*)((const unsigned short*)p + i);
    union { unsigned int u; float f; } c;
    c.u = (unsigned int)(v & 0xFFFFu) << 16;         r[0] = c.f;
    c.u = (unsigned int)((v >> 16) & 0xFFFFu) << 16; r[1] = c.f;
    c.u = (unsigned int)((v >> 32) & 0xFFFFu) << 16; r[2] = c.f;
    c.u = (unsigned int)((v >> 48) & 0xFFFFu) << 16; r[3] = c.f;
  }
  return r;
}

__device__ __forceinline__ float tanhf_fast(float x) {
  float ax = fabsf(x);
  float t = __expf(-2.0f*ax);
  float r = (1.0f - t)/(1.0f + t);
  return x < 0.0f ? -r : r;
}

struct MegaParams {
  const void* seq; const void* att; const int* etok; const void* emask;
  const int* hts; const void* wliner; const void* bliner; const void* wseg;
  const void* bseg; const void* whead; const void* bhead; const void* wtail;
  const void* btail; const void* wbil; const void* bbil; void* out;
  float* e_emb; __bf16* e_att; float* sp; __bf16* Xb; __bf16* whT; __bf16* wT;
  __bf16* hsb; __bf16* tsb; _Float16* part24;
};

// ============================ mega kernel =============================
// __launch_bounds__(256, 3): 3 waves/EU min => 3 blocks/CU co-resident,
// caps unified VGPR+AGPR at ~170/wave. LDS 36.9 KB * 3 = 110 KB < 160 KB.
__global__ __launch_bounds__(256, 3)
void k_mega(MegaParams P) {
  __shared__ __align__(16) char smem_raw[36864];
  __shared__ int sflag;
  const int tid = threadIdx.x;
  const int nb = gridDim.x;
  const int w = tid >> 6, lane = tid & 63, quad = lane >> 4, col = lane & 15;

  if (tid < 64) {
    unsigned int word = ((const unsigned int*)P.whead)[tid];
    union { unsigned int u; float f; } c; c.u = (word & 0xFFFFu) << 16;
    unsigned long long m = __ballot(fabsf(c.f) > 1.0f);
    if (tid == 0) sflag = (__popcll(m) >= 8) ? 1 : 0;
  }
  __syncthreads();
  const int f32 = sflag;

  cg::grid_group grid = cg::this_grid();
  float* smemf = (float*)smem_raw;

  // ================= P0: stage1 =================
  for (int blk = blockIdx.x; blk < B_TOTAL; blk += nb) {
    __syncthreads();
    if (blk < B_EATT0) {
      int be = blk, b = be / NEnt;
      int* sidx = (int*)smemf;
      float* sval = smemf + 16;
      if (tid < MM) {
        int t = P.etok[be*MM + tid];
        int ip = t + 1;
        float v = ldin(P.emask, be*MM + tid, f32);
        sval[tid] = (ip < SEQ) ? v : 0.0f;
        sidx[tid] = ip < 0 ? 0 : (ip > SEQ-1 ? SEQ-1 : ip);
      }
      __syncthreads();
      float cnt = 0.0f;
#pragma unroll
      for (int m = 0; m < MM; m++) cnt += sval[m];
      for (int d = tid; d < DIM; d += 256) {
        float x[MM];
#pragma unroll
        for (int m = 0; m < MM; m++)
          x[m] = ldin(P.seq, ((long long)(b*SEQ) + sidx[m])*DIM + d, f32);
        float mx = -1e30f;
#pragma unroll
        for (int m = 0; m < MM; m++) if (sval[m] > 0.0f && x[m] > mx) mx = x[m];
        float s = 0.0f;
#pragma unroll
        for (int m = 0; m < MM; m++) if (sval[m] > 0.0f) s += expf(x[m] - mx);
        P.e_emb[(long long)be*DIM + d] = (cnt > 0.0f) ? (mx + logf(s)) : 0.0f;
      }
    } else if (blk < B_SP0) {
      int t1 = blk - B_EATT0;
      int h = t1 % NH, be = t1 / NH, b = be / NEnt;
      int* sidx = (int*)smemf;
      float* sval = smemf + 16;
      if (tid < MM) {
        int t = P.etok[be*MM + tid];
        int ip = t + 1;
        float v = ldin(P.emask, be*MM + tid, f32);
        sval[tid] = (ip < SEQ) ? v : 0.0f;
        sidx[tid] = ip < 0 ? 0 : (ip > SEQ-1 ? SEQ-1 : ip);
      }
      __syncthreads();
      float cnt = 0.0f;
#pragma unroll
      for (int m = 0; m < MM; m++) cnt += sval[m];
      float rs = (cnt > 0.0f) ? 1.0f/fmaxf(cnt, 1.0f) : 0.0f;
      long long abase = ((long long)(b*NH + h))*SEQ*SEQ;
      int s0 = tid*4;
      f32x4 acc = (f32x4){0,0,0,0};
#pragma unroll
      for (int m = 0; m < MM; m++)
        if (sval[m] > 0.0f) {
          f32x4 v = ldin4(P.att, abase + (long long)sidx[m]*SEQ + s0, f32);
          acc += sval[m]*v;
        }
      bf16x4 ov;
#pragma unroll
      for (int k = 0; k < 4; k++) ov[k] = (__bf16)(acc[k]*rs);
      *(bf16x4*)(P.e_att + ((long long)(be*NH + h))*SEQ + s0) = ov;
    } else if (blk < B_WHT0) {
      int t2 = blk - B_SP0;
      int b = t2 >> 8;
      int wv = tid >> 6, l = tid & 63;
      int s = ((t2 & 255) << 2) + wv;
      long long rb = ((long long)(b*SEQ) + s)*DIM;
      float a0 = 0, a1 = 0, a2 = 0;
#pragma unroll
      for (int i = 0; i < DIM/64; i++) {
        int d = l + i*64;
        float x = ldin(P.seq, rb + d, f32);
        a0 += x*ldin(P.wliner, (long long)d*3 + 0, f32);
        a1 += x*ldin(P.wliner, (long long)d*3 + 1, f32);
        a2 += x*ldin(P.wliner, (long long)d*3 + 2, f32);
      }
#pragma unroll
      for (int o = 32; o; o >>= 1) {
        a0 += __shfl_down(a0, o);
        a1 += __shfl_down(a1, o);
        a2 += __shfl_down(a2, o);
      }
      if (l == 0) {
        P.sp[0*(BSZ*SEQ) + b*SEQ + s] = a0;
        P.sp[1*(BSZ*SEQ) + b*SEQ + s] = a1;
        P.sp[2*(BSZ*SEQ) + b*SEQ + s] = a2;
      }
    } else if (blk < B_WT0) {
      int t3 = blk - B_WHT0;
      int kb = t3 & 15, rest = t3 >> 4;
      int nbk = rest % 12, y = rest / 12;
      const void* W = y ? P.wtail : P.whead;
      for (int i = tid; i < 64*64; i += 256) {
        int r = i >> 6, c = i & 63;
        smemf[r*65 + c] = ldin(W, (long long)(kb*64 + r)*EMB + nbk*64 + c, f32);
      }
      __syncthreads();
      for (int j = tid; j < 64*64; j += 256) {
        int r = j >> 6, k = j & 63;
        P.whT[((long long)y*EMB + nbk*64 + r)*1024 + kb*64 + k] = (__bf16)smemf[k*65 + r];
      }
    } else if (blk < B_ZERO0) {
      int t4 = blk - B_WT0;
      int kb = t4 & 63, g = t4 >> 6;
      long long base = ((long long)g*4096 + kb*64)*97;
      for (int i = tid; i < 64*97; i += 256)
        smemf[(i/97)*98 + (i%97)] = ldin(P.wbil, base + i, f32);
      __syncthreads();
      for (int j = tid; j < 97*64; j += 256) {
        int l = j >> 6, k = j & 63;
        P.wT[((long long)g*97 + l)*4096 + kb*64 + k] = (__bf16)smemf[k*98 + l];
      }
    } else {
      int y = blk - B_ZERO0;
      uint4 z = {0,0,0,0};
      uint4* dst = (uint4*)(P.Xb + ((long long)(y*XROWS + NPAIR))*1024);
      for (int i = tid; i < 48*1024*2/16; i += 256) dst[i] = z;
    }
  }
  grid.sync();

  // ================= P1: per-pair pooling + seg + X build =================
  float (*cross)[4] = (float (*)[4])smem_raw;
  for (int p = blockIdx.x; p < NPAIR; p += nb) {
    __syncthreads();
    int b = p / PPairs;
    int hi = P.hts[p*2 + 0];
    int ti = P.hts[p*2 + 1];
    const __bf16* ei = P.e_att + ((long long)(b*NEnt + hi))*NH*SEQ;
    const __bf16* ej = P.e_att + ((long long)(b*NEnt + ti))*NH*SEQ;
    int s0 = tid*4;
    f32x4 q = (f32x4){0,0,0,0};
#pragma unroll
    for (int h = 0; h < NH; h++) {
      bf16x4 xi = *(const bf16x4*)(ei + h*SEQ + s0);
      bf16x4 xj = *(const bf16x4*)(ej + h*SEQ + s0);
#pragma unroll
      for (int k = 0; k < 4; k++) q[k] += (float)xi[k]*(float)xj[k];
    }
    f32x4 w0 = *(const f32x4*)(P.sp + 0*(BSZ*SEQ) + b*SEQ + s0);
    f32x4 w1 = *(const f32x4*)(P.sp + 1*(BSZ*SEQ) + b*SEQ + s0);
    f32x4 w2 = *(const f32x4*)(P.sp + 2*(BSZ*SEQ) + b*SEQ + s0);
    float dn = q[0]+q[1]+q[2]+q[3];
    float a0 = q[0]*w0[0]+q[1]*w0[1]+q[2]*w0[2]+q[3]*w0[3];
    float a1 = q[0]*w1[0]+q[1]*w1[1]+q[2]*w1[2]+q[3]*w1[3];
    float a2 = q[0]*w2[0]+q[1]*w2[1]+q[2]*w2[2]+q[3]*w2[3];
#pragma unroll
    for (int o = 32; o; o >>= 1) {
      dn += __shfl_down(dn, o);
      a0 += __shfl_down(a0, o);
      a1 += __shfl_down(a1, o);
      a2 += __shfl_down(a2, o);
    }
    if (lane == 0) { cross[0][w] = dn; cross[1][w] = a0; cross[2][w] = a1; cross[3][w] = a2; }
    __syncthreads();
    float DN = cross[0][0]+cross[0][1]+cross[0][2]+cross[0][3];
    float A0 = cross[1][0]+cross[1][1]+cross[1][2]+cross[1][3];
    float A1 = cross[2][0]+cross[2][1]+cross[2][2]+cross[2][3];
    float A2 = cross[3][0]+cross[3][1]+cross[3][2]+cross[3][3];
    const float inv = 1.0f/(float)NH;
    float scale = inv/(DN*inv + 1e-5f);
    float v0 = A0*scale + ldin(P.bliner, 0, f32);
    float v1 = A1*scale + ldin(P.bliner, 1, f32);
    float v2 = A2*scale + ldin(P.bliner, 2, f32);
    float o = ldin(P.bseg, tid, f32)
            + v0*ldin(P.wseg, 0*OUTC + tid, f32)
            + v1*ldin(P.wseg, 1*OUTC + tid, f32)
            + v2*ldin(P.wseg, 2*OUTC + tid, f32);
    __bf16* X0 = P.Xb + ((long long)(0*XROWS + p))*1024;
    __bf16* X1 = P.Xb + ((long long)(1*XROWS + p))*1024;
    X0[DIM + tid] = (__bf16)o;
    X1[DIM + tid] = (__bf16)o;
    const float* eh = P.e_emb + (long long)(b*NEnt + hi)*DIM;
    const float* et = P.e_emb + (long long)(b*NEnt + ti)*DIM;
    for (int k = tid; k < DIM; k += 256) {
      X0[k] = (__bf16)eh[k];
      X1[k] = (__bf16)et[k];
    }
  }
  grid.sync();

  // ================= P2: head/tail GEMM + tanh (64-row units) =============
  for (int u = blockIdx.x; u < 32*12*2; u += nb) {
    __syncthreads();
    int m0 = (u & 31) << 6;
    int rest = u >> 5;
    int n0 = (rest % 12) << 6;
    int y  = rest / 12;
    __bf16 (*Xa)[64][72] = (__bf16 (*)[64][72])smem_raw;
    __bf16 (*Bb)[64][72] = (__bf16 (*)[64][72])(smem_raw + 18432);
    const __bf16* Xg = P.Xb + (long long)y*XROWS*1024;
    const __bf16* Wg = P.whT + ((long long)y*EMB + n0)*1024;
    auto stage = [&](int kk, int pb) {
#pragma unroll
      for (int it = 0; it < 2; it++) {
        int r = (tid >> 3) + (it << 5);
        int c0 = (tid & 7) << 3;
        *(bf16x8*)&Xa[pb][r][c0] = *(const bf16x8*)(Xg + (long long)(m0 + r)*1024 + kk + c0);
        *(bf16x8*)&Bb[pb][r][c0] = *(const bf16x8*)(Wg + (long long)r*1024 + kk + c0);
      }
    };
    f32x4 acc[4];
#pragma unroll
    for (int nt = 0; nt < 4; nt++) acc[nt] = (f32x4){0,0,0,0};
    stage(0, 0);
    __syncthreads();
    for (int c = 0; c < 16; c++) {
      int pb = c & 1;
      if (c + 1 < 16) stage((c+1)*64, pb ^ 1);
#pragma unroll
      for (int s = 0; s < 2; s++) {
        bf16x8 av = *(bf16x8*)&Xa[pb][(w<<4) + col][s*32 + quad*8];
        bf16x8 bv[4];
#pragma unroll
        for (int nt = 0; nt < 4; nt++)
          bv[nt] = *(bf16x8*)&Bb[pb][nt*16 + col][s*32 + quad*8];
#pragma unroll
        for (int nt = 0; nt < 4; nt++)
          acc[nt] = __builtin_amdgcn_mfma_f32_16x16x32_bf16(av, bv[nt], acc[nt], 0, 0, 0);
      }
      __syncthreads();
    }
    const void* Bv = y ? P.btail : P.bhead;
    __bf16* outp = y ? P.tsb : P.hsb;
#pragma unroll
    for (int nt = 0; nt < 4; nt++) {
      int n = n0 + nt*16 + col;
      float bias = ldin(Bv, n, f32);
#pragma unroll
      for (int reg = 0; reg < 4; reg++) {
        int m = m0 + (w<<4) + quad*4 + reg;
        if (m < NPAIR)
          outp[(long long)m*EMB + n] = (__bf16)tanhf_fast(acc[nt][reg] + bias);
      }
    }
  }
  grid.sync();

  // ================= P3: bilinear MFMA (64-row x chunk units) =============
  // Single-depth B loads (no register prefetch): TLP at 3 blocks/CU hides L2.
  for (int u = blockIdx.x; u < 32*NCHUNK; u += nb) {
    __syncthreads();
    int m0 = (u & 31) << 6;
    int c  = u >> 5;
    int g = c >> 1, kh = c & 1;
    __bf16 (*hslT)[72] = (__bf16 (*)[72])smem_raw;
    {
      int srow = tid & 63;
      int grow = m0 + srow; if (grow > NPAIR-1) grow = NPAIR-1;
      int ah = (tid >> 6) << 3;
      const __bf16* hp = P.hsb + (long long)grow*EMB + g*BLKsz + kh*32 + ah;
      bf16x8 hv8 = *(const bf16x8*)hp;
#pragma unroll
      for (int j = 0; j < 8; j++) hslT[ah + j][srow] = hv8[j];
    }
    bf16x8 tsv[2];
    {
      int row = m0 + (w<<4) + col; if (row > NPAIR-1) row = NPAIR-1;
      const __bf16* tp = P.tsb + (long long)row*EMB + g*BLKsz + quad*8;
      tsv[0] = *(const bf16x8*)(tp);
      tsv[1] = *(const bf16x8*)(tp + 32);
    }
    __syncthreads();
    const __bf16* wg = P.wT + (long long)g*NL*4096 + kh*2048 + quad*8;
    int boff[7];
#pragma unroll
    for (int nt = 0; nt < 7; nt++) {
      int l = nt*16 + col; if (l > 96) l = 96;
      boff[nt] = l*4096;
    }
    f32x4 acc[7];
#pragma unroll
    for (int nt = 0; nt < 7; nt++) acc[nt] = (f32x4){0,0,0,0};
    for (int a = 0; a < 32; a++) {
      float hv = (float)hslT[a][(w<<4) + col];
#pragma unroll
      for (int half = 0; half < 2; half++) {
        bf16x8 bvv[7];
        int ko = a*64 + half*32;
#pragma unroll
        for (int nt = 0; nt < 7; nt++)
          bvv[nt] = *(const bf16x8*)(wg + boff[nt] + ko);
        bf16x8 af;
#pragma unroll
        for (int j = 0; j < 8; j++) af[j] = (__bf16)(hv * (float)tsv[half][j]);
#pragma unroll
        for (int nt = 0; nt < 7; nt++)
          acc[nt] = __builtin_amdgcn_mfma_f32_16x16x32_bf16(af, bvv[nt], acc[nt], 0, 0, 0);
      }
    }
    _Float16* ps = P.part24 + (long long)c*NPAIR*NL;
#pragma unroll
    for (int nt = 0; nt < 7; nt++)
#pragma unroll
      for (int reg = 0; reg < 4; reg++) {
        int n = m0 + (w<<4) + quad*4 + reg;
        int l = nt*16 + col;
        if (n < NPAIR && l < NL)
          ps[(long long)n*NL + l] = (_Float16)acc[nt][reg];
      }
  }
  grid.sync();

  // ================= P4: final reduction ==================================
  for (int i = blockIdx.x*256 + tid; i < NPAIR*NL; i += nb*256) {
    int l = i % NL;
    float v = ldin(P.bbil, l, f32);
#pragma unroll
    for (int c = 0; c < NCHUNK; c++) v += (float)P.part24[(long long)c*NPAIR*NL + i];
    if (f32) ((float*)P.out)[i] = v;
    else ((__hip_bfloat16*)P.out)[i] = __float2bfloat16(v);
  }
}

// ===================== fallback (non-cooperative) path =====================
__global__ void k_detect(const void* w_head, int* flag) {
  int tid = threadIdx.x;
  unsigned int word = ((const unsigned int*)w_head)[tid];
  union { unsigned int u; float f; } c;
  c.u = (word & 0xFFFFu) << 16;
  unsigned long long m = __ballot(fabsf(c.f) > 1.0f);
  if (tid == 0) flag[0] = (__popcll(m) >= 8) ? 1 : 0;
}

__global__ __launch_bounds__(256)
void k_fb(MegaParams P, const int* flag, int phase) {
  __shared__ __align__(16) char smem_raw[36864];
  const int tid = threadIdx.x;
  const int f32 = *flag;
  const int w = tid >> 6, lane = tid & 63, quad = lane >> 4, col = lane & 15;
  float* smemf = (float*)smem_raw;
  if (phase == 0) {
    int blk = blockIdx.x;
    if (blk < B_EATT0) {
      int be = blk, b = be / NEnt;
      int* sidx = (int*)smemf; float* sval = smemf + 16;
      if (tid < MM) {
        int t = P.etok[be*MM + tid]; int ip = t + 1;
        float v = ldin(P.emask, be*MM + tid, f32);
        sval[tid] = (ip < SEQ) ? v : 0.0f;
        sidx[tid] = ip < 0 ? 0 : (ip > SEQ-1 ? SEQ-1 : ip);
      }
      __syncthreads();
      float cnt = 0.0f;
#pragma unroll
      for (int m = 0; m < MM; m++) cnt += sval[m];
      for (int d = tid; d < DIM; d += 256) {
        float x[MM];
#pragma unroll
        for (int m = 0; m < MM; m++)
          x[m] = ldin(P.seq, ((long long)(b*SEQ) + sidx[m])*DIM + d, f32);
        float mx = -1e30f;
#pragma unroll
        for (int m = 0; m < MM; m++) if (sval[m] > 0.0f && x[m] > mx) mx = x[m];
        float s = 0.0f;
#pragma unroll
        for (int m = 0; m < MM; m++) if (sval[m] > 0.0f) s += expf(x[m] - mx);
        P.e_emb[(long long)be*DIM + d] = (cnt > 0.0f) ? (mx + logf(s)) : 0.0f;
      }
    } else if (blk < B_SP0) {
      int t1 = blk - B_EATT0;
      int h = t1 % NH, be = t1 / NH, b = be / NEnt;
      int* sidx = (int*)smemf; float* sval = smemf + 16;
      if (tid < MM) {
        int t = P.etok[be*MM + tid]; int ip = t + 1;
        float v = ldin(P.emask, be*MM + tid, f32);
        sval[tid] = (ip < SEQ) ? v : 0.0f;
        sidx[tid] = ip < 0 ? 0 : (ip > SEQ-1 ? SEQ-1 : ip);
      }
      __syncthreads();
      float cnt = 0.0f;
#pragma unroll
      for (int m = 0; m < MM; m++) cnt += sval[m];
      float rs = (cnt > 0.0f) ? 1.0f/fmaxf(cnt, 1.0f) : 0.0f;
      long long abase = ((long long)(b*NH + h))*SEQ*SEQ;
      int s0 = tid*4;
      f32x4 acc = (f32x4){0,0,0,0};
#pragma unroll
      for (int m = 0; m < MM; m++)
        if (sval[m] > 0.0f) acc += sval[m]*ldin4(P.att, abase + (long long)sidx[m]*SEQ + s0, f32);
      bf16x4 ov;
#pragma unroll
      for (int k = 0; k < 4; k++) ov[k] = (__bf16)(acc[k]*rs);
      *(bf16x4*)(P.e_att + ((long long)(be*NH + h))*SEQ + s0) = ov;
    } else if (blk < B_WHT0) {
      int t2 = blk - B_SP0; int b = t2 >> 8;
      int wv = tid >> 6, l = tid & 63;
      int s = ((t2 & 255) << 2) + wv;
      long long rb = ((long long)(b*SEQ) + s)*DIM;
      float a0 = 0, a1 = 0, a2 = 0;
#pragma unroll
      for (int i = 0; i < DIM/64; i++) {
        int d = l + i*64;
        float x = ldin(P.seq, rb + d, f32);
        a0 += x*ldin(P.wliner, (long long)d*3 + 0, f32);
        a1 += x*ldin(P.wliner, (long long)d*3 + 1, f32);
        a2 += x*ldin(P.wliner, (long long)d*3 + 2, f32);
      }
#pragma unroll
      for (int o = 32; o; o >>= 1) {
        a0 += __shfl_down(a0, o); a1 += __shfl_down(a1, o); a2 += __shfl_down(a2, o);
      }
      if (l == 0) {
        P.sp[0*(BSZ*SEQ) + b*SEQ + s] = a0;
        P.sp[1*(BSZ*SEQ) + b*SEQ + s] = a1;
        P.sp[2*(BSZ*SEQ) + b*SEQ + s] = a2;
      }
    } else if (blk < B_WT0) {
      int t3 = blk - B_WHT0;
      int kb = t3 & 15, rest = t3 >> 4;
      int nbk = rest % 12, y = rest / 12;
      const void* W = y ? P.wtail : P.whead;
      for (int i = tid; i < 64*64; i += 256) {
        int r = i >> 6, c = i & 63;
        smemf[r*65 + c] = ldin(W, (long long)(kb*64 + r)*EMB + nbk*64 + c, f32);
      }
      __syncthreads();
      for (int j = tid; j < 64*64; j += 256) {
        int r = j >> 6, k = j & 63;
        P.whT[((long long)y*EMB + nbk*64 + r)*1024 + kb*64 + k] = (__bf16)smemf[k*65 + r];
      }
    } else if (blk < B_ZERO0) {
      int t4 = blk - B_WT0;
      int kb = t4 & 63, g = t4 >> 6;
      long long base = ((long long)g*4096 + kb*64)*97;
      for (int i = tid; i < 64*97; i += 256)
        smemf[(i/97)*98 + (i%97)] = ldin(P.wbil, base + i, f32);
      __syncthreads();
      for (int j = tid; j < 97*64; j += 256) {
        int l = j >> 6, k = j & 63;
        P.wT[((long long)g*97 + l)*4096 + kb*64 + k] = (__bf16)smemf[k*98 + l];
      }
    } else {
      int y = blk - B_ZERO0;
      uint4 z = {0,0,0,0};
      uint4* dst = (uint4*)(P.Xb + ((long long)(y*XROWS + NPAIR))*1024);
      for (int i = tid; i < 48*1024*2/16; i += 256) dst[i] = z;
    }
  } else if (phase == 1) {
    float (*cross)[4] = (float (*)[4])smem_raw;
    int p = blockIdx.x;
    int b = p / PPairs;
    int hi = P.hts[p*2 + 0], ti = P.hts[p*2 + 1];
    const __bf16* ei = P.e_att + ((long long)(b*NEnt + hi))*NH*SEQ;
    const __bf16* ej = P.e_att + ((long long)(b*NEnt + ti))*NH*SEQ;
    int s0 = tid*4;
    f32x4 q = (f32x4){0,0,0,0};
#pragma unroll
    for (int h = 0; h < NH; h++) {
      bf16x4 xi = *(const bf16x4*)(ei + h*SEQ + s0);
      bf16x4 xj = *(const bf16x4*)(ej + h*SEQ + s0);
#pragma unroll
      for (int k = 0; k < 4; k++) q[k] += (float)xi[k]*(float)xj[k];
    }
    f32x4 w0 = *(const f32x4*)(P.sp + 0*(BSZ*SEQ) + b*SEQ + s0);
    f32x4 w1 = *(const f32x4*)(P.sp + 1*(BSZ*SEQ) + b*SEQ + s0);
    f32x4 w2 = *(const f32x4*)(P.sp + 2*(BSZ*SEQ) + b*SEQ + s0);
    float dn = q[0]+q[1]+q[2]+q[3];
    float a0 = q[0]*w0[0]+q[1]*w0[1]+q[2]*w0[2]+q[3]*w0[3];
    float a1 = q[0]*w1[0]+q[1]*w1[1]+q[2]*w1[2]+q[3]*w1[3];
    float a2 = q[0]*w2[0]+q[1]*w2[1]+q[2]*w2[2]+q[3]*w2[3];
#pragma unroll
    for (int o = 32; o; o >>= 1) {
      dn += __shfl_down(dn, o); a0 += __shfl_down(a0, o);
      a1 += __shfl_down(a1, o); a2 += __shfl_down(a2, o);
    }
    if (lane == 0) { cross[0][w] = dn; cross[1][w] = a0; cross[2][w] = a1; cross[3][w] = a2; }
    __syncthreads();
    float DN = cross[0][0]+cross[0][1]+cross[0][2]+cross[0][3];
    float A0 = cross[1][0]+cross[1][1]+cross[1][2]+cross[1][3];
    float A1 = cross[2][0]+cross[2][1]+cross[2][2]+cross[2][3];
    float A2 = cross[3][0]+cross[3][1]+cross[3][2]+cross[3][3];
    const float inv = 1.0f/(float)NH;
    float scale = inv/(DN*inv + 1e-5f);
    float v0 = A0*scale + ldin(P.bliner, 0, f32);
    float v1 = A1*scale + ldin(P.bliner, 1, f32);
    float v2 = A2*scale + ldin(P.bliner, 2, f32);
    float o = ldin(P.bseg, tid, f32)
            + v0*ldin(P.wseg, 0*OUTC + tid, f32)
            + v1*ldin(P.wseg, 1*OUTC + tid, f32)
            + v2*ldin(P.wseg, 2*OUTC + tid, f32);
    __bf16* X0 = P.Xb + ((long long)(0*XROWS + p))*1024;
    __bf16* X1 = P.Xb + ((long long)(1*XROWS + p))*1024;
    X0[DIM + tid] = (__bf16)o; X1[DIM + tid] = (__bf16)o;
    const float* eh = P.e_emb + (long long)(b*NEnt + hi)*DIM;
    const float* et = P.e_emb + (long long)(b*NEnt + ti)*DIM;
    for (int k = tid; k < DIM; k += 256) { X0[k] = (__bf16)eh[k]; X1[k] = (__bf16)et[k]; }
  } else if (phase == 2) {
    int u = blockIdx.x;
    int m0 = (u & 31) << 6;
    int rest = u >> 5;
    int n0 = (rest % 12) << 6;
    int y  = rest / 12;
    __bf16 (*Xa)[64][72] = (__bf16 (*)[64][72])smem_raw;
    __bf16 (*Bb)[64][72] = (__bf16 (*)[64][72])(smem_raw + 18432);
    const __bf16* Xg = P.Xb + (long long)y*XROWS*1024;
    const __bf16* Wg = P.whT + ((long long)y*EMB + n0)*1024;
    auto stage = [&](int kk, int pb) {
#pragma unroll
      for (int it = 0; it < 2; it++) {
        int r = (tid >> 3) + (it << 5);
        int c0 = (tid & 7) << 3;
        *(bf16x8*)&Xa[pb][r][c0] = *(const bf16x8*)(Xg + (long long)(m0 + r)*1024 + kk + c0);
        *(bf16x8*)&Bb[pb][r][c0] = *(const bf16x8*)(Wg + (long long)r*1024 + kk + c0);
      }
    };
    f32x4 acc[4];
#pragma unroll
    for (int nt = 0; nt < 4; nt++) acc[nt] = (f32x4){0,0,0,0};
    stage(0, 0);
    __syncthreads();
    for (int c = 0; c < 16; c++) {
      int pb = c & 1;
      if (c + 1 < 16) stage((c+1)*64, pb ^ 1);
#pragma unroll
      for (int s = 0; s < 2; s++) {
        bf16x8 av = *(bf16x8*)&Xa[pb][(w<<4) + col][s*32 + quad*8];
        bf16x8 bvv[4];
#pragma unroll
        for (int nt = 0; nt < 4; nt++) bvv[nt] = *(bf16x8*)&Bb[pb][nt*16 + col][s*32 + quad*8];
#pragma unroll
        for (int nt = 0; nt < 4; nt++)
          acc[nt] = __builtin_amdgcn_mfma_f32_16x16x32_bf16(av, bvv[nt], acc[nt], 0, 0, 0);
      }
      __syncthreads();
    }
    const void* Bv = y ? P.btail : P.bhead;
    __bf16* outp = y ? P.tsb : P.hsb;
#pragma unroll
    for (int nt = 0; nt < 4; nt++) {
      int n = n0 + nt*16 + col;
      float bias = ldin(Bv, n, f32);
#pragma unroll
      for (int reg = 0; reg < 4; reg++) {
        int m = m0 + (w<<4) + quad*4 + reg;
        if (m < NPAIR) outp[(long long)m*EMB + n] = (__bf16)tanhf_fast(acc[nt][reg] + bias);
      }
    }
  } else if (phase == 3) {
    int u = blockIdx.x;
    int m0 = (u & 31) << 6;
    int c  = u >> 5;
    int g = c >> 1, kh = c & 1;
    __bf16 (*hslT)[72] = (__bf16 (*)[72])smem_raw;
    {
      int srow = tid & 63;
      int grow = m0 + srow; if (grow > NPAIR-1) grow = NPAIR-1;
      int ah = (tid >> 6) << 3;
      const __bf16* hp = P.hsb + (long long)grow*EMB + g*BLKsz + kh*32 + ah;
      bf16x8 hv8 = *(const bf16x8*)hp;
#pragma unroll
      for (int j = 0; j < 8; j++) hslT[ah + j][srow] = hv8[j];
    }
    bf16x8 tsv[2];
    {
      int row = m0 + (w<<4) + col; if (row > NPAIR-1) row = NPAIR-1;
      const __bf16* tp = P.tsb + (long long)row*EMB + g*BLKsz + quad*8;
      tsv[0] = *(const bf16x8*)(tp); tsv[1] = *(const bf16x8*)(tp + 32);
    }
    __syncthreads();
    const __bf16* wg = P.wT + (long long)g*NL*4096 + kh*2048 + quad*8;
    int boff[7];
#pragma unroll
    for (int nt = 0; nt < 7; nt++) { int l = nt*16 + col; if (l > 96) l = 96; boff[nt] = l*4096; }
    f32x4 acc[7];
#pragma unroll
    for (int nt = 0; nt < 7; nt++) acc[nt] = (f32x4){0,0,0,0};
    for (int a = 0; a < 32; a++) {
      float hv = (float)hslT[a][(w<<4) + col];
#pragma unroll
      for (int half = 0; half < 2; half++) {
        bf16x8 bvv[7];
        int ko = a*64 + half*32;
#pragma unroll
        for (int nt = 0; nt < 7; nt++) bvv[nt] = *(const bf16x8*)(wg + boff[nt] + ko);
        bf16x8 af;
#pragma unroll
        for (int j = 0; j < 8; j++) af[j] = (__bf16)(hv * (float)tsv[half][j]);
#pragma unroll
        for (int nt = 0; nt < 7; nt++)
          acc[nt] = __builtin_amdgcn_mfma_f32_16x16x32_bf16(af, bvv[nt], acc[nt], 0, 0, 0);
      }
    }
    _Float16* ps = P.part24 + (long long)c*NPAIR*NL;
#pragma unroll
    for (int nt = 0; nt < 7; nt++)
#pragma unroll
      for (int reg = 0; reg < 4; reg++) {
        int n = m0 + (w<<4) + quad*4 + reg;
        int l = nt*16 + col;
        if (n < NPAIR && l < NL) ps[(long long)n*NL + l] = (_Float16)acc[nt][reg];
      }
  } else {
    int i = blockIdx.x*256 + tid;
    if (i < NPAIR*NL) {
      int l = i % NL;
      float v = ldin(P.bbil, l, f32);
#pragma unroll
      for (int c = 0; c < NCHUNK; c++) v += (float)P.part24[(long long)c*NPAIR*NL + i];
      if (f32) ((float*)P.out)[i] = v;
      else ((__hip_bfloat16*)P.out)[i] = __float2bfloat16(v);
    }
  }
}

extern "C" void kernel_launch(void* const* d_in, const int* in_sizes, int n_in,
                              void* d_out, int out_size, void* d_ws, size_t ws_size,
                              hipStream_t stream) {
  char* ws = (char*)d_ws;
  MegaParams p;
  p.seq    = d_in[0];  p.att    = d_in[1];
  p.etok   = (const int*)d_in[2];
  p.emask  = d_in[3];
  p.hts    = (const int*)d_in[4];
  p.wliner = d_in[5];  p.bliner = d_in[6];
  p.wseg   = d_in[7];  p.bseg   = d_in[8];
  p.whead  = d_in[9];  p.bhead  = d_in[10];
  p.wtail  = d_in[11]; p.btail  = d_in[12];
  p.wbil   = d_in[13]; p.bbil   = d_in[14];
  p.out    = d_out;
  p.e_emb  = (float*)(ws + OFF_EEMB);
  p.e_att  = (__bf16*)(ws + OFF_EATT);
  p.sp     = (float*)(ws + OFF_SP);
  p.Xb     = (__bf16*)(ws + OFF_XB);
  p.whT    = (__bf16*)(ws + OFF_WHT);
  p.wT     = (__bf16*)(ws + OFF_WT);
  p.hsb    = (__bf16*)(ws + OFF_HSB);
  p.tsb    = (__bf16*)(ws + OFF_TSB);
  p.part24 = (_Float16*)(ws + OFF_PART);

  int ncu = 0;
  if (hipDeviceGetAttribute(&ncu, hipDeviceAttributeMultiprocessorCount, 0) != hipSuccess || ncu <= 0)
    ncu = 256;
  int occ = 0;
  if (hipOccupancyMaxActiveBlocksPerMultiprocessor(&occ, k_mega, 256, 0) != hipSuccess)
    occ = 0;
  if (occ > 3) occ = 3;

  bool launched = false;
  if (occ >= 2) {
    void* args[] = { (void*)&p };
    for (int k = occ; k >= 2 && !launched; k--) {
      hipError_t err = hipLaunchCooperativeKernel((const void*)k_mega,
                                                  dim3(k*ncu), dim3(256), args, 0, stream);
      if (err == hipSuccess) launched = true;
    }
  }
  if (!launched) {
    // multi-launch fallback (R1-equivalent, ~419 us)
    int* flag = (int*)ws;
    k_detect<<<1, 64, 0, stream>>>(p.whead, flag);
    k_fb<<<B_TOTAL, 256, 0, stream>>>(p, flag, 0);
    k_fb<<<NPAIR, 256, 0, stream>>>(p, flag, 1);
    k_fb<<<32*12*2, 256, 0, stream>>>(p, flag, 2);
    k_fb<<<32*NCHUNK, 256, 0, stream>>>(p, flag, 3);
    k_fb<<<(NPAIR*NL + 255)/256, 256, 0, stream>>>(p, flag, 4);
  }
}

// Round 4
// 486.373 us; speedup vs baseline: 1.4391x; 1.0043x over previous
//
#include <hip/hip_runtime.h>
#include <hip/hip_bf16.h>
#include <hip/hip_cooperative_groups.h>
#include <math.h>

namespace cg = cooperative_groups;

#define BSZ 4
#define SEQ 1024
#define DIM 768
#define NH 12
#define NEnt 42
#define MM 8
#define PPairs 500
#define INC 3
#define OUTC 256
#define EMB 768
#define BLKsz 64
#define NL 97
#define NPAIR (BSZ*PPairs)   // 2000
#define XROWS 2048
#define NCHUNK 24

typedef __bf16 bf16x8 __attribute__((ext_vector_type(8)));
typedef __bf16 bf16x4 __attribute__((ext_vector_type(4)));
typedef float f32x4 __attribute__((ext_vector_type(4)));

// ---- workspace byte offsets ----
#define OFF_EEMB  4096
#define OFF_EATT  520192
#define OFF_SP    4648960
#define OFF_XB    4698112
#define OFF_WHT   13086720
#define OFF_WT    16232448
#define OFF_HSB   25767936
#define OFF_TSB   28839936
#define OFF_PART  31911936

// stage1 virtual-block ranges
#define B_EEMB0 0
#define B_EATT0 168
#define B_SP0   2184
#define B_WHT0  3208
#define B_WT0   3592
#define B_ZERO0 4360
#define B_TOTAL 4362

__device__ __forceinline__ float ldin(const void* p, long long i, int f32) {
  if (f32) return ((const float*)p)[i];
  unsigned int u = (unsigned int)(((const unsigned short*)p)[i]) << 16;
  union { unsigned int u; float f; } c; c.u = u;
  return c.f;
}

__device__ __forceinline__ f32x4 ldin4(const void* p, long long i, int f32) {
  f32x4 r;
  if (f32) {
    r = *(const f32x4*)((const float*)p + i);
  } else {
    unsigned long long v = *(const unsigned long long*)((const unsigned short*)p + i);
    union { unsigned int u; float f; } c;
    c.u = (unsigned int)(v & 0xFFFFu) << 16;         r[0] = c.f;
    c.u = (unsigned int)((v >> 16) & 0xFFFFu) << 16; r[1] = c.f;
    c.u = (unsigned int)((v >> 32) & 0xFFFFu) << 16; r[2] = c.f;
    c.u = (unsigned int)((v >> 48) & 0xFFFFu) << 16; r[3] = c.f;
  }
  return r;
}

__device__ __forceinline__ float tanhf_fast(float x) {
  float ax = fabsf(x);
  float t = __expf(-2.0f*ax);
  float r = (1.0f - t)/(1.0f + t);
  return x < 0.0f ? -r : r;
}

struct MegaParams {
  const void* seq; const void* att; const int* etok; const void* emask;
  const int* hts; const void* wliner; const void* bliner; const void* wseg;
  const void* bseg; const void* whead; const void* bhead; const void* wtail;
  const void* btail; const void* wbil; const void* bbil; void* out;
  float* e_emb; __bf16* e_att; float* sp; __bf16* Xb; __bf16* whT; __bf16* wT;
  __bf16* hsb; __bf16* tsb; _Float16* part24;
};

// ============================ mega kernel =============================
// __launch_bounds__(256, 2): relaxed reg cap (no spills; R3's (256,3) forced
// 84 VGPR -> +64MB scratch write-back). Compiler lands ~156 VGPR => 3 blk/CU
// co-resident anyway (512/156 = 3 waves/SIMD; LDS 36.9KB*3 = 110KB < 160KB).
__global__ __launch_bounds__(256, 2)
void k_mega(MegaParams P) {
  __shared__ __align__(16) char smem_raw[36864];
  __shared__ int sflag;
  const int tid = threadIdx.x;
  const int nb = gridDim.x;
  const int w = tid >> 6, lane = tid & 63, quad = lane >> 4, col = lane & 15;

  if (tid < 64) {
    unsigned int word = ((const unsigned int*)P.whead)[tid];
    union { unsigned int u; float f; } c; c.u = (word & 0xFFFFu) << 16;
    unsigned long long m = __ballot(fabsf(c.f) > 1.0f);
    if (tid == 0) sflag = (__popcll(m) >= 8) ? 1 : 0;
  }
  __syncthreads();
  const int f32 = sflag;

  cg::grid_group grid = cg::this_grid();
  float* smemf = (float*)smem_raw;

  // ================= P0: stage1 =================
  for (int blk = blockIdx.x; blk < B_TOTAL; blk += nb) {
    __syncthreads();
    if (blk < B_EATT0) {
      int be = blk, b = be / NEnt;
      int* sidx = (int*)smemf;
      float* sval = smemf + 16;
      if (tid < MM) {
        int t = P.etok[be*MM + tid];
        int ip = t + 1;
        float v = ldin(P.emask, be*MM + tid, f32);
        sval[tid] = (ip < SEQ) ? v : 0.0f;
        sidx[tid] = ip < 0 ? 0 : (ip > SEQ-1 ? SEQ-1 : ip);
      }
      __syncthreads();
      float cnt = 0.0f;
#pragma unroll
      for (int m = 0; m < MM; m++) cnt += sval[m];
      for (int d = tid; d < DIM; d += 256) {
        float x[MM];
#pragma unroll
        for (int m = 0; m < MM; m++)
          x[m] = ldin(P.seq, ((long long)(b*SEQ) + sidx[m])*DIM + d, f32);
        float mx = -1e30f;
#pragma unroll
        for (int m = 0; m < MM; m++) if (sval[m] > 0.0f && x[m] > mx) mx = x[m];
        float s = 0.0f;
#pragma unroll
        for (int m = 0; m < MM; m++) if (sval[m] > 0.0f) s += expf(x[m] - mx);
        P.e_emb[(long long)be*DIM + d] = (cnt > 0.0f) ? (mx + logf(s)) : 0.0f;
      }
    } else if (blk < B_SP0) {
      int t1 = blk - B_EATT0;
      int h = t1 % NH, be = t1 / NH, b = be / NEnt;
      int* sidx = (int*)smemf;
      float* sval = smemf + 16;
      if (tid < MM) {
        int t = P.etok[be*MM + tid];
        int ip = t + 1;
        float v = ldin(P.emask, be*MM + tid, f32);
        sval[tid] = (ip < SEQ) ? v : 0.0f;
        sidx[tid] = ip < 0 ? 0 : (ip > SEQ-1 ? SEQ-1 : ip);
      }
      __syncthreads();
      float cnt = 0.0f;
#pragma unroll
      for (int m = 0; m < MM; m++) cnt += sval[m];
      float rs = (cnt > 0.0f) ? 1.0f/fmaxf(cnt, 1.0f) : 0.0f;
      long long abase = ((long long)(b*NH + h))*SEQ*SEQ;
      int s0 = tid*4;
      f32x4 acc = (f32x4){0,0,0,0};
#pragma unroll
      for (int m = 0; m < MM; m++)
        if (sval[m] > 0.0f) {
          f32x4 v = ldin4(P.att, abase + (long long)sidx[m]*SEQ + s0, f32);
          acc += sval[m]*v;
        }
      bf16x4 ov;
#pragma unroll
      for (int k = 0; k < 4; k++) ov[k] = (__bf16)(acc[k]*rs);
      *(bf16x4*)(P.e_att + ((long long)(be*NH + h))*SEQ + s0) = ov;
    } else if (blk < B_WHT0) {
      int t2 = blk - B_SP0;
      int b = t2 >> 8;
      int wv = tid >> 6, l = tid & 63;
      int s = ((t2 & 255) << 2) + wv;
      long long rb = ((long long)(b*SEQ) + s)*DIM;
      float a0 = 0, a1 = 0, a2 = 0;
#pragma unroll
      for (int i = 0; i < DIM/64; i++) {
        int d = l + i*64;
        float x = ldin(P.seq, rb + d, f32);
        a0 += x*ldin(P.wliner, (long long)d*3 + 0, f32);
        a1 += x*ldin(P.wliner, (long long)d*3 + 1, f32);
        a2 += x*ldin(P.wliner, (long long)d*3 + 2, f32);
      }
#pragma unroll
      for (int o = 32; o; o >>= 1) {
        a0 += __shfl_down(a0, o);
        a1 += __shfl_down(a1, o);
        a2 += __shfl_down(a2, o);
      }
      if (l == 0) {
        P.sp[0*(BSZ*SEQ) + b*SEQ + s] = a0;
        P.sp[1*(BSZ*SEQ) + b*SEQ + s] = a1;
        P.sp[2*(BSZ*SEQ) + b*SEQ + s] = a2;
      }
    } else if (blk < B_WT0) {
      int t3 = blk - B_WHT0;
      int kb = t3 & 15, rest = t3 >> 4;
      int nbk = rest % 12, y = rest / 12;
      const void* W = y ? P.wtail : P.whead;
      for (int i = tid; i < 64*64; i += 256) {
        int r = i >> 6, c = i & 63;
        smemf[r*65 + c] = ldin(W, (long long)(kb*64 + r)*EMB + nbk*64 + c, f32);
      }
      __syncthreads();
      for (int j = tid; j < 64*64; j += 256) {
        int r = j >> 6, k = j & 63;
        P.whT[((long long)y*EMB + nbk*64 + r)*1024 + kb*64 + k] = (__bf16)smemf[k*65 + r];
      }
    } else if (blk < B_ZERO0) {
      int t4 = blk - B_WT0;
      int kb = t4 & 63, g = t4 >> 6;
      long long base = ((long long)g*4096 + kb*64)*97;
      for (int i = tid; i < 64*97; i += 256)
        smemf[(i/97)*98 + (i%97)] = ldin(P.wbil, base + i, f32);
      __syncthreads();
      for (int j = tid; j < 97*64; j += 256) {
        int l = j >> 6, k = j & 63;
        P.wT[((long long)g*97 + l)*4096 + kb*64 + k] = (__bf16)smemf[k*98 + l];
      }
    } else {
      int y = blk - B_ZERO0;
      uint4 z = {0,0,0,0};
      uint4* dst = (uint4*)(P.Xb + ((long long)(y*XROWS + NPAIR))*1024);
      for (int i = tid; i < 48*1024*2/16; i += 256) dst[i] = z;
    }
  }
  grid.sync();

  // ================= P1: per-pair pooling + seg + X build =================
  float (*cross)[4] = (float (*)[4])smem_raw;
  for (int p = blockIdx.x; p < NPAIR; p += nb) {
    __syncthreads();
    int b = p / PPairs;
    int hi = P.hts[p*2 + 0];
    int ti = P.hts[p*2 + 1];
    const __bf16* ei = P.e_att + ((long long)(b*NEnt + hi))*NH*SEQ;
    const __bf16* ej = P.e_att + ((long long)(b*NEnt + ti))*NH*SEQ;
    int s0 = tid*4;
    f32x4 q = (f32x4){0,0,0,0};
#pragma unroll
    for (int h = 0; h < NH; h++) {
      bf16x4 xi = *(const bf16x4*)(ei + h*SEQ + s0);
      bf16x4 xj = *(const bf16x4*)(ej + h*SEQ + s0);
#pragma unroll
      for (int k = 0; k < 4; k++) q[k] += (float)xi[k]*(float)xj[k];
    }
    f32x4 w0 = *(const f32x4*)(P.sp + 0*(BSZ*SEQ) + b*SEQ + s0);
    f32x4 w1 = *(const f32x4*)(P.sp + 1*(BSZ*SEQ) + b*SEQ + s0);
    f32x4 w2 = *(const f32x4*)(P.sp + 2*(BSZ*SEQ) + b*SEQ + s0);
    float dn = q[0]+q[1]+q[2]+q[3];
    float a0 = q[0]*w0[0]+q[1]*w0[1]+q[2]*w0[2]+q[3]*w0[3];
    float a1 = q[0]*w1[0]+q[1]*w1[1]+q[2]*w1[2]+q[3]*w1[3];
    float a2 = q[0]*w2[0]+q[1]*w2[1]+q[2]*w2[2]+q[3]*w2[3];
#pragma unroll
    for (int o = 32; o; o >>= 1) {
      dn += __shfl_down(dn, o);
      a0 += __shfl_down(a0, o);
      a1 += __shfl_down(a1, o);
      a2 += __shfl_down(a2, o);
    }
    if (lane == 0) { cross[0][w] = dn; cross[1][w] = a0; cross[2][w] = a1; cross[3][w] = a2; }
    __syncthreads();
    float DN = cross[0][0]+cross[0][1]+cross[0][2]+cross[0][3];
    float A0 = cross[1][0]+cross[1][1]+cross[1][2]+cross[1][3];
    float A1 = cross[2][0]+cross[2][1]+cross[2][2]+cross[2][3];
    float A2 = cross[3][0]+cross[3][1]+cross[3][2]+cross[3][3];
    const float inv = 1.0f/(float)NH;
    float scale = inv/(DN*inv + 1e-5f);
    float v0 = A0*scale + ldin(P.bliner, 0, f32);
    float v1 = A1*scale + ldin(P.bliner, 1, f32);
    float v2 = A2*scale + ldin(P.bliner, 2, f32);
    float o = ldin(P.bseg, tid, f32)
            + v0*ldin(P.wseg, 0*OUTC + tid, f32)
            + v1*ldin(P.wseg, 1*OUTC + tid, f32)
            + v2*ldin(P.wseg, 2*OUTC + tid, f32);
    __bf16* X0 = P.Xb + ((long long)(0*XROWS + p))*1024;
    __bf16* X1 = P.Xb + ((long long)(1*XROWS + p))*1024;
    X0[DIM + tid] = (__bf16)o;
    X1[DIM + tid] = (__bf16)o;
    const float* eh = P.e_emb + (long long)(b*NEnt + hi)*DIM;
    const float* et = P.e_emb + (long long)(b*NEnt + ti)*DIM;
    for (int k = tid; k < DIM; k += 256) {
      X0[k] = (__bf16)eh[k];
      X1[k] = (__bf16)et[k];
    }
  }
  grid.sync();

  // ================= P2: head/tail GEMM + tanh (64-row units) =============
  for (int u = blockIdx.x; u < 32*12*2; u += nb) {
    __syncthreads();
    int m0 = (u & 31) << 6;
    int rest = u >> 5;
    int n0 = (rest % 12) << 6;
    int y  = rest / 12;
    __bf16 (*Xa)[64][72] = (__bf16 (*)[64][72])smem_raw;
    __bf16 (*Bb)[64][72] = (__bf16 (*)[64][72])(smem_raw + 18432);
    const __bf16* Xg = P.Xb + (long long)y*XROWS*1024;
    const __bf16* Wg = P.whT + ((long long)y*EMB + n0)*1024;
    auto stage = [&](int kk, int pb) {
#pragma unroll
      for (int it = 0; it < 2; it++) {
        int r = (tid >> 3) + (it << 5);
        int c0 = (tid & 7) << 3;
        *(bf16x8*)&Xa[pb][r][c0] = *(const bf16x8*)(Xg + (long long)(m0 + r)*1024 + kk + c0);
        *(bf16x8*)&Bb[pb][r][c0] = *(const bf16x8*)(Wg + (long long)r*1024 + kk + c0);
      }
    };
    f32x4 acc[4];
#pragma unroll
    for (int nt = 0; nt < 4; nt++) acc[nt] = (f32x4){0,0,0,0};
    stage(0, 0);
    __syncthreads();
    for (int c = 0; c < 16; c++) {
      int pb = c & 1;
      if (c + 1 < 16) stage((c+1)*64, pb ^ 1);
#pragma unroll
      for (int s = 0; s < 2; s++) {
        bf16x8 av = *(bf16x8*)&Xa[pb][(w<<4) + col][s*32 + quad*8];
        bf16x8 bv[4];
#pragma unroll
        for (int nt = 0; nt < 4; nt++)
          bv[nt] = *(bf16x8*)&Bb[pb][nt*16 + col][s*32 + quad*8];
#pragma unroll
        for (int nt = 0; nt < 4; nt++)
          acc[nt] = __builtin_amdgcn_mfma_f32_16x16x32_bf16(av, bv[nt], acc[nt], 0, 0, 0);
      }
      __syncthreads();
    }
    const void* Bv = y ? P.btail : P.bhead;
    __bf16* outp = y ? P.tsb : P.hsb;
#pragma unroll
    for (int nt = 0; nt < 4; nt++) {
      int n = n0 + nt*16 + col;
      float bias = ldin(Bv, n, f32);
#pragma unroll
      for (int reg = 0; reg < 4; reg++) {
        int m = m0 + (w<<4) + quad*4 + reg;
        if (m < NPAIR)
          outp[(long long)m*EMB + n] = (__bf16)tanhf_fast(acc[nt][reg] + bias);
      }
    }
  }
  grid.sync();

  // ================= P3: bilinear MFMA (64-row x chunk units) =============
  // depth-2 register prefetch on B (R2 form; fits in ~156 VGPR, no spill).
  for (int u = blockIdx.x; u < 32*NCHUNK; u += nb) {
    __syncthreads();
    int m0 = (u & 31) << 6;
    int c  = u >> 5;
    int g = c >> 1, kh = c & 1;
    __bf16 (*hslT)[72] = (__bf16 (*)[72])smem_raw;
    {
      int srow = tid & 63;
      int grow = m0 + srow; if (grow > NPAIR-1) grow = NPAIR-1;
      int ah = (tid >> 6) << 3;
      const __bf16* hp = P.hsb + (long long)grow*EMB + g*BLKsz + kh*32 + ah;
      bf16x8 hv8 = *(const bf16x8*)hp;
#pragma unroll
      for (int j = 0; j < 8; j++) hslT[ah + j][srow] = hv8[j];
    }
    bf16x8 tsv[2];
    {
      int row = m0 + (w<<4) + col; if (row > NPAIR-1) row = NPAIR-1;
      const __bf16* tp = P.tsb + (long long)row*EMB + g*BLKsz + quad*8;
      tsv[0] = *(const bf16x8*)(tp);
      tsv[1] = *(const bf16x8*)(tp + 32);
    }
    __syncthreads();
    const __bf16* wg = P.wT + (long long)g*NL*4096 + kh*2048 + quad*8;
    int boff[7];
#pragma unroll
    for (int nt = 0; nt < 7; nt++) {
      int l = nt*16 + col; if (l > 96) l = 96;
      boff[nt] = l*4096;
    }
    f32x4 acc[7];
#pragma unroll
    for (int nt = 0; nt < 7; nt++) acc[nt] = (f32x4){0,0,0,0};
    bf16x8 bv[2][7];
#pragma unroll
    for (int nt = 0; nt < 7; nt++) bv[0][nt] = *(const bf16x8*)(wg + boff[nt]);
#pragma unroll
    for (int nt = 0; nt < 7; nt++) bv[1][nt] = *(const bf16x8*)(wg + boff[nt] + 32);
    for (int a = 0; a < 32; a++) {
      float hv = (float)hslT[a][(w<<4) + col];
#pragma unroll
      for (int half = 0; half < 2; half++) {
        bf16x8 af;
#pragma unroll
        for (int j = 0; j < 8; j++) af[j] = (__bf16)(hv * (float)tsv[half][j]);
#pragma unroll
        for (int nt = 0; nt < 7; nt++)
          acc[nt] = __builtin_amdgcn_mfma_f32_16x16x32_bf16(af, bv[half][nt], acc[nt], 0, 0, 0);
        int knext = (a+1)*64 + half*32;
        if (knext >= 2048) knext = a*64 + half*32;  // harmless refill at tail
#pragma unroll
        for (int nt = 0; nt < 7; nt++)
          bv[half][nt] = *(const bf16x8*)(wg + boff[nt] + knext);
      }
    }
    _Float16* ps = P.part24 + (long long)c*NPAIR*NL;
#pragma unroll
    for (int nt = 0; nt < 7; nt++)
#pragma unroll
      for (int reg = 0; reg < 4; reg++) {
        int n = m0 + (w<<4) + quad*4 + reg;
        int l = nt*16 + col;
        if (n < NPAIR && l < NL)
          ps[(long long)n*NL + l] = (_Float16)acc[nt][reg];
      }
  }
  grid.sync();

  // ================= P4: final reduction ==================================
  for (int i = blockIdx.x*256 + tid; i < NPAIR*NL; i += nb*256) {
    int l = i % NL;
    float v = ldin(P.bbil, l, f32);
#pragma unroll
    for (int c = 0; c < NCHUNK; c++) v += (float)P.part24[(long long)c*NPAIR*NL + i];
    if (f32) ((float*)P.out)[i] = v;
    else ((__hip_bfloat16*)P.out)[i] = __float2bfloat16(v);
  }
}

// ===================== fallback (non-cooperative) path =====================
__global__ void k_detect(const void* w_head, int* flag) {
  int tid = threadIdx.x;
  unsigned int word = ((const unsigned int*)w_head)[tid];
  union { unsigned int u; float f; } c;
  c.u = (word & 0xFFFFu) << 16;
  unsigned long long m = __ballot(fabsf(c.f) > 1.0f);
  if (tid == 0) flag[0] = (__popcll(m) >= 8) ? 1 : 0;
}

__global__ __launch_bounds__(256)
void k_fb(MegaParams P, const int* flag, int phase) {
  __shared__ __align__(16) char smem_raw[36864];
  const int tid = threadIdx.x;
  const int f32 = *flag;
  const int w = tid >> 6, lane = tid & 63, quad = lane >> 4, col = lane & 15;
  float* smemf = (float*)smem_raw;
  if (phase == 0) {
    int blk = blockIdx.x;
    if (blk < B_EATT0) {
      int be = blk, b = be / NEnt;
      int* sidx = (int*)smemf; float* sval = smemf + 16;
      if (tid < MM) {
        int t = P.etok[be*MM + tid]; int ip = t + 1;
        float v = ldin(P.emask, be*MM + tid, f32);
        sval[tid] = (ip < SEQ) ? v : 0.0f;
        sidx[tid] = ip < 0 ? 0 : (ip > SEQ-1 ? SEQ-1 : ip);
      }
      __syncthreads();
      float cnt = 0.0f;
#pragma unroll
      for (int m = 0; m < MM; m++) cnt += sval[m];
      for (int d = tid; d < DIM; d += 256) {
        float x[MM];
#pragma unroll
        for (int m = 0; m < MM; m++)
          x[m] = ldin(P.seq, ((long long)(b*SEQ) + sidx[m])*DIM + d, f32);
        float mx = -1e30f;
#pragma unroll
        for (int m = 0; m < MM; m++) if (sval[m] > 0.0f && x[m] > mx) mx = x[m];
        float s = 0.0f;
#pragma unroll
        for (int m = 0; m < MM; m++) if (sval[m] > 0.0f) s += expf(x[m] - mx);
        P.e_emb[(long long)be*DIM + d] = (cnt > 0.0f) ? (mx + logf(s)) : 0.0f;
      }
    } else if (blk < B_SP0) {
      int t1 = blk - B_EATT0;
      int h = t1 % NH, be = t1 / NH, b = be / NEnt;
      int* sidx = (int*)smemf; float* sval = smemf + 16;
      if (tid < MM) {
        int t = P.etok[be*MM + tid]; int ip = t + 1;
        float v = ldin(P.emask, be*MM + tid, f32);
        sval[tid] = (ip < SEQ) ? v : 0.0f;
        sidx[tid] = ip < 0 ? 0 : (ip > SEQ-1 ? SEQ-1 : ip);
      }
      __syncthreads();
      float cnt = 0.0f;
#pragma unroll
      for (int m = 0; m < MM; m++) cnt += sval[m];
      float rs = (cnt > 0.0f) ? 1.0f/fmaxf(cnt, 1.0f) : 0.0f;
      long long abase = ((long long)(b*NH + h))*SEQ*SEQ;
      int s0 = tid*4;
      f32x4 acc = (f32x4){0,0,0,0};
#pragma unroll
      for (int m = 0; m < MM; m++)
        if (sval[m] > 0.0f) acc += sval[m]*ldin4(P.att, abase + (long long)sidx[m]*SEQ + s0, f32);
      bf16x4 ov;
#pragma unroll
      for (int k = 0; k < 4; k++) ov[k] = (__bf16)(acc[k]*rs);
      *(bf16x4*)(P.e_att + ((long long)(be*NH + h))*SEQ + s0) = ov;
    } else if (blk < B_WHT0) {
      int t2 = blk - B_SP0; int b = t2 >> 8;
      int wv = tid >> 6, l = tid & 63;
      int s = ((t2 & 255) << 2) + wv;
      long long rb = ((long long)(b*SEQ) + s)*DIM;
      float a0 = 0, a1 = 0, a2 = 0;
#pragma unroll
      for (int i = 0; i < DIM/64; i++) {
        int d = l + i*64;
        float x = ldin(P.seq, rb + d, f32);
        a0 += x*ldin(P.wliner, (long long)d*3 + 0, f32);
        a1 += x*ldin(P.wliner, (long long)d*3 + 1, f32);
        a2 += x*ldin(P.wliner, (long long)d*3 + 2, f32);
      }
#pragma unroll
      for (int o = 32; o; o >>= 1) {
        a0 += __shfl_down(a0, o); a1 += __shfl_down(a1, o); a2 += __shfl_down(a2, o);
      }
      if (l == 0) {
        P.sp[0*(BSZ*SEQ) + b*SEQ + s] = a0;
        P.sp[1*(BSZ*SEQ) + b*SEQ + s] = a1;
        P.sp[2*(BSZ*SEQ) + b*SEQ + s] = a2;
      }
    } else if (blk < B_WT0) {
      int t3 = blk - B_WHT0;
      int kb = t3 & 15, rest = t3 >> 4;
      int nbk = rest % 12, y = rest / 12;
      const void* W = y ? P.wtail : P.whead;
      for (int i = tid; i < 64*64; i += 256) {
        int r = i >> 6, c = i & 63;
        smemf[r*65 + c] = ldin(W, (long long)(kb*64 + r)*EMB + nbk*64 + c, f32);
      }
      __syncthreads();
      for (int j = tid; j < 64*64; j += 256) {
        int r = j >> 6, k = j & 63;
        P.whT[((long long)y*EMB + nbk*64 + r)*1024 + kb*64 + k] = (__bf16)smemf[k*65 + r];
      }
    } else if (blk < B_ZERO0) {
      int t4 = blk - B_WT0;
      int kb = t4 & 63, g = t4 >> 6;
      long long base = ((long long)g*4096 + kb*64)*97;
      for (int i = tid; i < 64*97; i += 256)
        smemf[(i/97)*98 + (i%97)] = ldin(P.wbil, base + i, f32);
      __syncthreads();
      for (int j = tid; j < 97*64; j += 256) {
        int l = j >> 6, k = j & 63;
        P.wT[((long long)g*97 + l)*4096 + kb*64 + k] = (__bf16)smemf[k*98 + l];
      }
    } else {
      int y = blk - B_ZERO0;
      uint4 z = {0,0,0,0};
      uint4* dst = (uint4*)(P.Xb + ((long long)(y*XROWS + NPAIR))*1024);
      for (int i = tid; i < 48*1024*2/16; i += 256) dst[i] = z;
    }
  } else if (phase == 1) {
    float (*cross)[4] = (float (*)[4])smem_raw;
    int p = blockIdx.x;
    int b = p / PPairs;
    int hi = P.hts[p*2 + 0], ti = P.hts[p*2 + 1];
    const __bf16* ei = P.e_att + ((long long)(b*NEnt + hi))*NH*SEQ;
    const __bf16* ej = P.e_att + ((long long)(b*NEnt + ti))*NH*SEQ;
    int s0 = tid*4;
    f32x4 q = (f32x4){0,0,0,0};
#pragma unroll
    for (int h = 0; h < NH; h++) {
      bf16x4 xi = *(const bf16x4*)(ei + h*SEQ + s0);
      bf16x4 xj = *(const bf16x4*)(ej + h*SEQ + s0);
#pragma unroll
      for (int k = 0; k < 4; k++) q[k] += (float)xi[k]*(float)xj[k];
    }
    f32x4 w0 = *(const f32x4*)(P.sp + 0*(BSZ*SEQ) + b*SEQ + s0);
    f32x4 w1 = *(const f32x4*)(P.sp + 1*(BSZ*SEQ) + b*SEQ + s0);
    f32x4 w2 = *(const f32x4*)(P.sp + 2*(BSZ*SEQ) + b*SEQ + s0);
    float dn = q[0]+q[1]+q[2]+q[3];
    float a0 = q[0]*w0[0]+q[1]*w0[1]+q[2]*w0[2]+q[3]*w0[3];
    float a1 = q[0]*w1[0]+q[1]*w1[1]+q[2]*w1[2]+q[3]*w1[3];
    float a2 = q[0]*w2[0]+q[1]*w2[1]+q[2]*w2[2]+q[3]*w2[3];
#pragma unroll
    for (int o = 32; o; o >>= 1) {
      dn += __shfl_down(dn, o); a0 += __shfl_down(a0, o);
      a1 += __shfl_down(a1, o); a2 += __shfl_down(a2, o);
    }
    if (lane == 0) { cross[0][w] = dn; cross[1][w] = a0; cross[2][w] = a1; cross[3][w] = a2; }
    __syncthreads();
    float DN = cross[0][0]+cross[0][1]+cross[0][2]+cross[0][3];
    float A0 = cross[1][0]+cross[1][1]+cross[1][2]+cross[1][3];
    float A1 = cross[2][0]+cross[2][1]+cross[2][2]+cross[2][3];
    float A2 = cross[3][0]+cross[3][1]+cross[3][2]+cross[3][3];
    const float inv = 1.0f/(float)NH;
    float scale = inv/(DN*inv + 1e-5f);
    float v0 = A0*scale + ldin(P.bliner, 0, f32);
    float v1 = A1*scale + ldin(P.bliner, 1, f32);
    float v2 = A2*scale + ldin(P.bliner, 2, f32);
    float o = ldin(P.bseg, tid, f32)
            + v0*ldin(P.wseg, 0*OUTC + tid, f32)
            + v1*ldin(P.wseg, 1*OUTC + tid, f32)
            + v2*ldin(P.wseg, 2*OUTC + tid, f32);
    __bf16* X0 = P.Xb + ((long long)(0*XROWS + p))*1024;
    __bf16* X1 = P.Xb + ((long long)(1*XROWS + p))*1024;
    X0[DIM + tid] = (__bf16)o; X1[DIM + tid] = (__bf16)o;
    const float* eh = P.e_emb + (long long)(b*NEnt + hi)*DIM;
    const float* et = P.e_emb + (long long)(b*NEnt + ti)*DIM;
    for (int k = tid; k < DIM; k += 256) { X0[k] = (__bf16)eh[k]; X1[k] = (__bf16)et[k]; }
  } else if (phase == 2) {
    int u = blockIdx.x;
    int m0 = (u & 31) << 6;
    int rest = u >> 5;
    int n0 = (rest % 12) << 6;
    int y  = rest / 12;
    __bf16 (*Xa)[64][72] = (__bf16 (*)[64][72])smem_raw;
    __bf16 (*Bb)[64][72] = (__bf16 (*)[64][72])(smem_raw + 18432);
    const __bf16* Xg = P.Xb + (long long)y*XROWS*1024;
    const __bf16* Wg = P.whT + ((long long)y*EMB + n0)*1024;
    auto stage = [&](int kk, int pb) {
#pragma unroll
      for (int it = 0; it < 2; it++) {
        int r = (tid >> 3) + (it << 5);
        int c0 = (tid & 7) << 3;
        *(bf16x8*)&Xa[pb][r][c0] = *(const bf16x8*)(Xg + (long long)(m0 + r)*1024 + kk + c0);
        *(bf16x8*)&Bb[pb][r][c0] = *(const bf16x8*)(Wg + (long long)r*1024 + kk + c0);
      }
    };
    f32x4 acc[4];
#pragma unroll
    for (int nt = 0; nt < 4; nt++) acc[nt] = (f32x4){0,0,0,0};
    stage(0, 0);
    __syncthreads();
    for (int c = 0; c < 16; c++) {
      int pb = c & 1;
      if (c + 1 < 16) stage((c+1)*64, pb ^ 1);
#pragma unroll
      for (int s = 0; s < 2; s++) {
        bf16x8 av = *(bf16x8*)&Xa[pb][(w<<4) + col][s*32 + quad*8];
        bf16x8 bvv[4];
#pragma unroll
        for (int nt = 0; nt < 4; nt++) bvv[nt] = *(bf16x8*)&Bb[pb][nt*16 + col][s*32 + quad*8];
#pragma unroll
        for (int nt = 0; nt < 4; nt++)
          acc[nt] = __builtin_amdgcn_mfma_f32_16x16x32_bf16(av, bvv[nt], acc[nt], 0, 0, 0);
      }
      __syncthreads();
    }
    const void* Bv = y ? P.btail : P.bhead;
    __bf16* outp = y ? P.tsb : P.hsb;
#pragma unroll
    for (int nt = 0; nt < 4; nt++) {
      int n = n0 + nt*16 + col;
      float bias = ldin(Bv, n, f32);
#pragma unroll
      for (int reg = 0; reg < 4; reg++) {
        int m = m0 + (w<<4) + quad*4 + reg;
        if (m < NPAIR) outp[(long long)m*EMB + n] = (__bf16)tanhf_fast(acc[nt][reg] + bias);
      }
    }
  } else if (phase == 3) {
    int u = blockIdx.x;
    int m0 = (u & 31) << 6;
    int c  = u >> 5;
    int g = c >> 1, kh = c & 1;
    __bf16 (*hslT)[72] = (__bf16 (*)[72])smem_raw;
    {
      int srow = tid & 63;
      int grow = m0 + srow; if (grow > NPAIR-1) grow = NPAIR-1;
      int ah = (tid >> 6) << 3;
      const __bf16* hp = P.hsb + (long long)grow*EMB + g*BLKsz + kh*32 + ah;
      bf16x8 hv8 = *(const bf16x8*)hp;
#pragma unroll
      for (int j = 0; j < 8; j++) hslT[ah + j][srow] = hv8[j];
    }
    bf16x8 tsv[2];
    {
      int row = m0 + (w<<4) + col; if (row > NPAIR-1) row = NPAIR-1;
      const __bf16* tp = P.tsb + (long long)row*EMB + g*BLKsz + quad*8;
      tsv[0] = *(const bf16x8*)(tp); tsv[1] = *(const bf16x8*)(tp + 32);
    }
    __syncthreads();
    const __bf16* wg = P.wT + (long long)g*NL*4096 + kh*2048 + quad*8;
    int boff[7];
#pragma unroll
    for (int nt = 0; nt < 7; nt++) { int l = nt*16 + col; if (l > 96) l = 96; boff[nt] = l*4096; }
    f32x4 acc[7];
#pragma unroll
    for (int nt = 0; nt < 7; nt++) acc[nt] = (f32x4){0,0,0,0};
    bf16x8 bv[2][7];
#pragma unroll
    for (int nt = 0; nt < 7; nt++) bv[0][nt] = *(const bf16x8*)(wg + boff[nt]);
#pragma unroll
    for (int nt = 0; nt < 7; nt++) bv[1][nt] = *(const bf16x8*)(wg + boff[nt] + 32);
    for (int a = 0; a < 32; a++) {
      float hv = (float)hslT[a][(w<<4) + col];
#pragma unroll
      for (int half = 0; half < 2; half++) {
        bf16x8 af;
#pragma unroll
        for (int j = 0; j < 8; j++) af[j] = (__bf16)(hv * (float)tsv[half][j]);
#pragma unroll
        for (int nt = 0; nt < 7; nt++)
          acc[nt] = __builtin_amdgcn_mfma_f32_16x16x32_bf16(af, bv[half][nt], acc[nt], 0, 0, 0);
        int knext = (a+1)*64 + half*32;
        if (knext >= 2048) knext = a*64 + half*32;
#pragma unroll
        for (int nt = 0; nt < 7; nt++) bv[half][nt] = *(const bf16x8*)(wg + boff[nt] + knext);
      }
    }
    _Float16* ps = P.part24 + (long long)c*NPAIR*NL;
#pragma unroll
    for (int nt = 0; nt < 7; nt++)
#pragma unroll
      for (int reg = 0; reg < 4; reg++) {
        int n = m0 + (w<<4) + quad*4 + reg;
        int l = nt*16 + col;
        if (n < NPAIR && l < NL) ps[(long long)n*NL + l] = (_Float16)acc[nt][reg];
      }
  } else {
    int i = blockIdx.x*256 + tid;
    if (i < NPAIR*NL) {
      int l = i % NL;
      float v = ldin(P.bbil, l, f32);
#pragma unroll
      for (int c = 0; c < NCHUNK; c++) v += (float)P.part24[(long long)c*NPAIR*NL + i];
      if (f32) ((float*)P.out)[i] = v;
      else ((__hip_bfloat16*)P.out)[i] = __float2bfloat16(v);
    }
  }
}

extern "C" void kernel_launch(void* const* d_in, const int* in_sizes, int n_in,
                              void* d_out, int out_size, void* d_ws, size_t ws_size,
                              hipStream_t stream) {
  char* ws = (char*)d_ws;
  MegaParams p;
  p.seq    = d_in[0];  p.att    = d_in[1];
  p.etok   = (const int*)d_in[2];
  p.emask  = d_in[3];
  p.hts    = (const int*)d_in[4];
  p.wliner = d_in[5];  p.bliner = d_in[6];
  p.wseg   = d_in[7];  p.bseg   = d_in[8];
  p.whead  = d_in[9];  p.bhead  = d_in[10];
  p.wtail  = d_in[11]; p.btail  = d_in[12];
  p.wbil   = d_in[13]; p.bbil   = d_in[14];
  p.out    = d_out;
  p.e_emb  = (float*)(ws + OFF_EEMB);
  p.e_att  = (__bf16*)(ws + OFF_EATT);
  p.sp     = (float*)(ws + OFF_SP);
  p.Xb     = (__bf16*)(ws + OFF_XB);
  p.whT    = (__bf16*)(ws + OFF_WHT);
  p.wT     = (__bf16*)(ws + OFF_WT);
  p.hsb    = (__bf16*)(ws + OFF_HSB);
  p.tsb    = (__bf16*)(ws + OFF_TSB);
  p.part24 = (_Float16*)(ws + OFF_PART);

  int ncu = 0;
  if (hipDeviceGetAttribute(&ncu, hipDeviceAttributeMultiprocessorCount, 0) != hipSuccess || ncu <= 0)
    ncu = 256;
  int occ = 0;
  if (hipOccupancyMaxActiveBlocksPerMultiprocessor(&occ, k_mega, 256, 0) != hipSuccess)
    occ = 0;
  if (occ > 4) occ = 4;

  bool launched = false;
  if (occ >= 2) {
    void* args[] = { (void*)&p };
    for (int k = occ; k >= 2 && !launched; k--) {
      hipError_t err = hipLaunchCooperativeKernel((const void*)k_mega,
                                                  dim3(k*ncu), dim3(256), args, 0, stream);
      if (err == hipSuccess) launched = true;
    }
  }
  if (!launched) {
    // multi-launch fallback (R1-equivalent, ~419 us)
    int* flag = (int*)ws;
    k_detect<<<1, 64, 0, stream>>>(p.whead, flag);
    k_fb<<<B_TOTAL, 256, 0, stream>>>(p, flag, 0);
    k_fb<<<NPAIR, 256, 0, stream>>>(p, flag, 1);
    k_fb<<<32*12*2, 256, 0, stream>>>(p, flag, 2);
    k_fb<<<32*NCHUNK, 256, 0, stream>>>(p, flag, 3);
    k_fb<<<(NPAIR*NL + 255)/256, 256, 0, stream>>>(p, flag, 4);
  }
}

// Round 5
// 416.292 us; speedup vs baseline: 1.6813x; 1.1683x over previous
//
#include <hip/hip_runtime.h>
#include <hip/hip_bf16.h>
#include <math.h>

#define BSZ 4
#define SEQ 1024
#define DIM 768
#define NH 12
#define NEnt 42
#define MM 8
#define PPairs 500
#define INC 3
#define OUTC 256
#define EMB 768
#define BLKsz 64
#define NL 97
#define NPAIR (BSZ*PPairs)   // 2000
#define XROWS 2048
#define NCHUNK 24

typedef __bf16 bf16x8 __attribute__((ext_vector_type(8)));
typedef __bf16 bf16x4 __attribute__((ext_vector_type(4)));
typedef float f32x4 __attribute__((ext_vector_type(4)));
typedef _Float16 f16x4 __attribute__((ext_vector_type(4)));

// ---- workspace byte offsets ----
#define OFF_EEMB  4096
#define OFF_EATT  520192
#define OFF_SP    4648960
#define OFF_XB    4698112
#define OFF_WHT   13086720
#define OFF_WT    16232448
#define OFF_HSB   25767936
#define OFF_TSB   28839936
#define OFF_PART  31911936

// stage1 block ranges
#define B_EEMB0 0
#define B_EATT0 168
#define B_SP0   2184
#define B_WHT0  3208
#define B_WT0   3592
#define B_ZERO0 4360
#define B_TOTAL 4362

__device__ __forceinline__ float ldin(const void* p, long long i, int f32) {
  if (f32) return ((const float*)p)[i];
  unsigned int u = (unsigned int)(((const unsigned short*)p)[i]) << 16;
  union { unsigned int u; float f; } c; c.u = u;
  return c.f;
}

__device__ __forceinline__ f32x4 ldin4(const void* p, long long i, int f32) {
  f32x4 r;
  if (f32) {
    r = *(const f32x4*)((const float*)p + i);
  } else {
    unsigned long long v = *(const unsigned long long*)((const unsigned short*)p + i);
    union { unsigned int u; float f; } c;
    c.u = (unsigned int)(v & 0xFFFFu) << 16;         r[0] = c.f;
    c.u = (unsigned int)((v >> 16) & 0xFFFFu) << 16; r[1] = c.f;
    c.u = (unsigned int)((v >> 32) & 0xFFFFu) << 16; r[2] = c.f;
    c.u = (unsigned int)((v >> 48) & 0xFFFFu) << 16; r[3] = c.f;
  }
  return r;
}

__device__ __forceinline__ float tanhf_fast(float x) {
  float ax = fabsf(x);
  float t = __expf(-2.0f*ax);
  float r = (1.0f - t)/(1.0f + t);
  return x < 0.0f ? -r : r;
}

// Fused independent stage: inline dtype-detect (flag published by block 0),
// e_emb, e_att, sp, whT, wT, Xb zero-pad.
__global__ __launch_bounds__(256)
void k_stage1(const void* seq, const void* att, const int* etok,
              const void* emask, const void* wliner,
              const void* whead, const void* wtail, const void* wbil,
              int* flagOut,
              float* e_emb, __bf16* e_att, float* sp,
              __bf16* whT, __bf16* wT, __bf16* Xb) {
  __shared__ float smem[64*98];   // 24.5 KiB, shared by all branches
  __shared__ int sflag;
  int blk = blockIdx.x;
  int tid = threadIdx.x;          // 256

  // inline dtype detect (whead is L2-hot after first block touches it)
  if (tid < 64) {
    unsigned int word = ((const unsigned int*)whead)[tid];
    union { unsigned int u; float f; } c; c.u = (word & 0xFFFFu) << 16;
    unsigned long long m = __ballot(fabsf(c.f) > 1.0f);
    if (tid == 0) sflag = (__popcll(m) >= 8) ? 1 : 0;
  }
  __syncthreads();
  const int f32 = sflag;
  if (blk == 0 && tid == 0) flagOut[0] = f32;   // for downstream kernels

  if (blk < B_EATT0) {
    // ---- e_emb: logsumexp over valid mentions (vectorized f32x4) ----
    int be = blk, b = be / NEnt;
    int* sidx = (int*)smem;
    float* sval = smem + 16;
    if (tid < MM) {
      int t = etok[be*MM + tid];
      int ip = t + 1;
      float v = ldin(emask, be*MM + tid, f32);
      sval[tid] = (ip < SEQ) ? v : 0.0f;
      sidx[tid] = ip < 0 ? 0 : (ip > SEQ-1 ? SEQ-1 : ip);
    }
    __syncthreads();
    float cnt = 0.0f;
#pragma unroll
    for (int m = 0; m < MM; m++) cnt += sval[m];
    if (tid < 192) {
      int d0 = tid*4;   // 192*4 = 768 = DIM
      f32x4 x[MM];
#pragma unroll
      for (int m = 0; m < MM; m++)
        x[m] = ldin4(seq, ((long long)(b*SEQ) + sidx[m])*DIM + d0, f32);
      f32x4 outv;
#pragma unroll
      for (int j = 0; j < 4; j++) {
        float mx = -1e30f;
#pragma unroll
        for (int m = 0; m < MM; m++) if (sval[m] > 0.0f && x[m][j] > mx) mx = x[m][j];
        float s = 0.0f;
#pragma unroll
        for (int m = 0; m < MM; m++) if (sval[m] > 0.0f) s += expf(x[m][j] - mx);
        outv[j] = (cnt > 0.0f) ? (mx + logf(s)) : 0.0f;
      }
      *(f32x4*)(e_emb + (long long)be*DIM + d0) = outv;
    }
  } else if (blk < B_SP0) {
    // ---- e_att[be][h][s] (coalesced layout) ----
    int t1 = blk - B_EATT0;
    int h = t1 % NH, be = t1 / NH, b = be / NEnt;
    int* sidx = (int*)smem;
    float* sval = smem + 16;
    if (tid < MM) {
      int t = etok[be*MM + tid];
      int ip = t + 1;
      float v = ldin(emask, be*MM + tid, f32);
      sval[tid] = (ip < SEQ) ? v : 0.0f;
      sidx[tid] = ip < 0 ? 0 : (ip > SEQ-1 ? SEQ-1 : ip);
    }
    __syncthreads();
    float cnt = 0.0f;
#pragma unroll
    for (int m = 0; m < MM; m++) cnt += sval[m];
    float rs = (cnt > 0.0f) ? 1.0f/fmaxf(cnt, 1.0f) : 0.0f;
    long long abase = ((long long)(b*NH + h))*SEQ*SEQ;
    int s0 = tid*4;
    f32x4 acc = (f32x4){0,0,0,0};
#pragma unroll
    for (int m = 0; m < MM; m++)
      if (sval[m] > 0.0f) {
        f32x4 v = ldin4(att, abase + (long long)sidx[m]*SEQ + s0, f32);
        acc += sval[m]*v;
      }
    bf16x4 ov;
#pragma unroll
    for (int k = 0; k < 4; k++) ov[k] = (__bf16)(acc[k]*rs);
    *(bf16x4*)(e_att + ((long long)(be*NH + h))*SEQ + s0) = ov;
  } else if (blk < B_WHT0) {
    // ---- sp planar [3][b][s]; one wave per (b,s) ----
    int t2 = blk - B_SP0;            // 0..1023
    int b = t2 >> 8;
    int wv = tid >> 6, l = tid & 63;
    int s = ((t2 & 255) << 2) + wv;
    long long rb = ((long long)(b*SEQ) + s)*DIM;
    float a0 = 0, a1 = 0, a2 = 0;
#pragma unroll
    for (int i = 0; i < DIM/64; i++) {
      int d = l + i*64;
      float x = ldin(seq, rb + d, f32);
      a0 += x*ldin(wliner, (long long)d*3 + 0, f32);
      a1 += x*ldin(wliner, (long long)d*3 + 1, f32);
      a2 += x*ldin(wliner, (long long)d*3 + 2, f32);
    }
#pragma unroll
    for (int o = 32; o; o >>= 1) {
      a0 += __shfl_down(a0, o);
      a1 += __shfl_down(a1, o);
      a2 += __shfl_down(a2, o);
    }
    if (l == 0) {
      sp[0*(BSZ*SEQ) + b*SEQ + s] = a0;
      sp[1*(BSZ*SEQ) + b*SEQ + s] = a1;
      sp[2*(BSZ*SEQ) + b*SEQ + s] = a2;
    }
  } else if (blk < B_WT0) {
    // ---- whT: W_head/W_tail [1024][768] -> [y][768][1024] bf16 ----
    int t3 = blk - B_WHT0;           // 0..383
    int kb = t3 & 15, rest = t3 >> 4;
    int nb = rest % 12, y = rest / 12;
    const void* W = y ? wtail : whead;
    for (int i = tid; i < 64*64; i += 256) {
      int r = i >> 6, c = i & 63;
      smem[r*65 + c] = ldin(W, (long long)(kb*64 + r)*EMB + nb*64 + c, f32);
    }
    __syncthreads();
    for (int j = tid; j < 64*64; j += 256) {
      int r = j >> 6, k = j & 63;
      whT[((long long)y*EMB + nb*64 + r)*1024 + kb*64 + k] = (__bf16)smem[k*65 + r];
    }
  } else if (blk < B_ZERO0) {
    // ---- wT: W_bil[(g*4096+k)*97+l] -> wT[(g*97+l)*4096+k] bf16 ----
    int t4 = blk - B_WT0;            // 0..767
    int kb = t4 & 63, g = t4 >> 6;
    long long base = ((long long)g*4096 + kb*64)*97;
    for (int i = tid; i < 64*97; i += 256)
      smem[(i/97)*98 + (i%97)] = ldin(wbil, base + i, f32);
    __syncthreads();
    for (int j = tid; j < 97*64; j += 256) {
      int l = j >> 6, k = j & 63;
      wT[((long long)g*97 + l)*4096 + kb*64 + k] = (__bf16)smem[k*98 + l];
    }
  } else {
    // ---- zero-pad Xb rows [2000,2048) ----
    int y = blk - B_ZERO0;
    uint4 z = {0,0,0,0};
    uint4* dst = (uint4*)(Xb + ((long long)(y*XROWS + NPAIR))*1024);
    for (int i = tid; i < 48*1024*2/16; i += 256) dst[i] = z;
  }
}

// Per-pair pooling + seg projection, fused with X-row build.
// 12 heads split across two thread-halves -> bf16x8 (16B) loads.
__global__ __launch_bounds__(256)
void k_pair(const __bf16* e_att, const float* sp, const float* e_emb,
            const int* hts, const void* bliner, const void* wseg,
            const void* bseg, const int* flag, __bf16* Xb) {
  __shared__ float cross[4][4];
  int p = blockIdx.x;
  int b = p / PPairs;
  int tid = threadIdx.x;          // 256
  int f32 = *flag;
  int hi = hts[p*2 + 0];
  int ti = hts[p*2 + 1];
  const __bf16* ei = e_att + ((long long)(b*NEnt + hi))*NH*SEQ;
  const __bf16* ej = e_att + ((long long)(b*NEnt + ti))*NH*SEQ;
  int hh = tid >> 7;              // head-half: 0 -> h 0..5, 1 -> h 6..11
  int st = tid & 127;
  int s0 = st*8;                  // 128 threads cover s=0..1023
  float q[8];
#pragma unroll
  for (int k = 0; k < 8; k++) q[k] = 0.0f;
#pragma unroll
  for (int hq = 0; hq < 6; hq++) {
    int h = hh*6 + hq;
    bf16x8 xi = *(const bf16x8*)(ei + h*SEQ + s0);
    bf16x8 xj = *(const bf16x8*)(ej + h*SEQ + s0);
#pragma unroll
    for (int k = 0; k < 8; k++) q[k] += (float)xi[k]*(float)xj[k];
  }
  f32x4 w0a = *(const f32x4*)(sp + 0*(BSZ*SEQ) + b*SEQ + s0);
  f32x4 w0b = *(const f32x4*)(sp + 0*(BSZ*SEQ) + b*SEQ + s0 + 4);
  f32x4 w1a = *(const f32x4*)(sp + 1*(BSZ*SEQ) + b*SEQ + s0);
  f32x4 w1b = *(const f32x4*)(sp + 1*(BSZ*SEQ) + b*SEQ + s0 + 4);
  f32x4 w2a = *(const f32x4*)(sp + 2*(BSZ*SEQ) + b*SEQ + s0);
  f32x4 w2b = *(const f32x4*)(sp + 2*(BSZ*SEQ) + b*SEQ + s0 + 4);
  float dn = 0, a0 = 0, a1 = 0, a2 = 0;
#pragma unroll
  for (int k = 0; k < 4; k++) {
    dn += q[k] + q[k+4];
    a0 += q[k]*w0a[k] + q[k+4]*w0b[k];
    a1 += q[k]*w1a[k] + q[k+4]*w1b[k];
    a2 += q[k]*w2a[k] + q[k+4]*w2b[k];
  }
#pragma unroll
  for (int o = 32; o; o >>= 1) {
    dn += __shfl_down(dn, o);
    a0 += __shfl_down(a0, o);
    a1 += __shfl_down(a1, o);
    a2 += __shfl_down(a2, o);
  }
  int wv = tid >> 6, l = tid & 63;
  if (l == 0) { cross[0][wv] = dn; cross[1][wv] = a0; cross[2][wv] = a1; cross[3][wv] = a2; }
  __syncthreads();
  float DN = cross[0][0]+cross[0][1]+cross[0][2]+cross[0][3];
  float A0 = cross[1][0]+cross[1][1]+cross[1][2]+cross[1][3];
  float A1 = cross[2][0]+cross[2][1]+cross[2][2]+cross[2][3];
  float A2 = cross[3][0]+cross[3][1]+cross[3][2]+cross[3][3];
  const float inv = 1.0f/(float)NH;
  float scale = inv/(DN*inv + 1e-5f);
  float v0 = A0*scale + ldin(bliner, 0, f32);
  float v1 = A1*scale + ldin(bliner, 1, f32);
  float v2 = A2*scale + ldin(bliner, 2, f32);
  float o = ldin(bseg, tid, f32)
          + v0*ldin(wseg, 0*OUTC + tid, f32)
          + v1*ldin(wseg, 1*OUTC + tid, f32)
          + v2*ldin(wseg, 2*OUTC + tid, f32);
  __bf16* X0 = Xb + ((long long)(0*XROWS + p))*1024;
  __bf16* X1 = Xb + ((long long)(1*XROWS + p))*1024;
  X0[DIM + tid] = (__bf16)o;
  X1[DIM + tid] = (__bf16)o;
  const float* eh = e_emb + (long long)(b*NEnt + hi)*DIM;
  const float* et = e_emb + (long long)(b*NEnt + ti)*DIM;
  if (tid < 192) {
    int k0 = tid*4;
    f32x4 vh = *(const f32x4*)(eh + k0);
    f32x4 vt = *(const f32x4*)(et + k0);
    bf16x4 oh, ot;
#pragma unroll
    for (int j = 0; j < 4; j++) { oh[j] = (__bf16)vh[j]; ot[j] = (__bf16)vt[j]; }
    *(bf16x4*)(X0 + k0) = oh;
    *(bf16x4*)(X1 + k0) = ot;
  }
}

// MFMA head/tail: out = tanh(X @ W + b). 256 thr = 4 waves; wave = 32 rows x 64 cols.
__global__ __launch_bounds__(256, 1)
void k_htmm(const __bf16* Xb, const __bf16* whT,
            const void* bhead, const void* btail, const int* flag,
            __bf16* hsb, __bf16* tsb) {
  __shared__ __bf16 Xa[2][128][72];
  __shared__ __bf16 Bb[2][64][72];
  int tid = threadIdx.x;            // 256
  int w = tid >> 6, lane = tid & 63, quad = lane >> 4, col = lane & 15;
  int m0 = blockIdx.x*128;          // 16 m-blocks
  int n0 = blockIdx.y*64;           // 12 n-blocks
  int y  = blockIdx.z;
  int f32 = *flag;
  const __bf16* Xg = Xb + (long long)y*XROWS*1024;
  const __bf16* Wg = whT + ((long long)y*EMB + n0)*1024;

  auto stage = [&](int kk, int p) {
#pragma unroll
    for (int it = 0; it < 4; it++) {
      int r = (tid >> 3) + it*32;
      int c0 = (tid & 7)*8;
      bf16x8 v = *(const bf16x8*)(Xg + (long long)(m0 + r)*1024 + kk + c0);
      *(bf16x8*)&Xa[p][r][c0] = v;
    }
#pragma unroll
    for (int it = 0; it < 2; it++) {
      int r = (tid >> 3) + it*32;
      int c0 = (tid & 7)*8;
      bf16x8 v = *(const bf16x8*)(Wg + (long long)r*1024 + kk + c0);
      *(bf16x8*)&Bb[p][r][c0] = v;
    }
  };

  f32x4 acc[2][4];
#pragma unroll
  for (int mf = 0; mf < 2; mf++)
#pragma unroll
    for (int nt = 0; nt < 4; nt++) acc[mf][nt] = (f32x4){0,0,0,0};

  stage(0, 0);
  __syncthreads();
  for (int c = 0; c < 16; c++) {
    int p = c & 1;
    if (c + 1 < 16) stage((c+1)*64, p ^ 1);
#pragma unroll
    for (int s = 0; s < 2; s++) {
      bf16x8 av[2], bv[4];
#pragma unroll
      for (int mf = 0; mf < 2; mf++)
        av[mf] = *(bf16x8*)&Xa[p][w*32 + mf*16 + col][s*32 + quad*8];
#pragma unroll
      for (int nt = 0; nt < 4; nt++)
        bv[nt] = *(bf16x8*)&Bb[p][nt*16 + col][s*32 + quad*8];
#pragma unroll
      for (int mf = 0; mf < 2; mf++)
#pragma unroll
        for (int nt = 0; nt < 4; nt++)
          acc[mf][nt] = __builtin_amdgcn_mfma_f32_16x16x32_bf16(av[mf], bv[nt],
                                                                acc[mf][nt], 0, 0, 0);
    }
    __syncthreads();
  }

  const void* Bv = y ? btail : bhead;
  __bf16* out = y ? tsb : hsb;
#pragma unroll
  for (int nt = 0; nt < 4; nt++) {
    int n = n0 + nt*16 + col;
    float bias = ldin(Bv, n, f32);
#pragma unroll
    for (int mf = 0; mf < 2; mf++)
#pragma unroll
      for (int reg = 0; reg < 4; reg++) {
        int m = m0 + w*32 + mf*16 + quad*4 + reg;
        if (m < NPAIR)
          out[(long long)m*EMB + n] = (__bf16)tanhf_fast(acc[mf][nt][reg] + bias);
      }
  }
}

// MFMA bilinear: 64-row m-tiles, grid 32x24. 128 thr = 2 waves;
// wave = 32 rows (2 mf) x 112 cols (7 nt). Depth-2 B register prefetch.
__global__ __launch_bounds__(128, 2)
void k_bilmfma(const __bf16* hsb, const __bf16* tsb,
               const __bf16* wT, _Float16* part24) {
  __shared__ __bf16 hslT[32][72];   // [a_local][row]
  int tid = threadIdx.x;            // 128
  int w = tid >> 6, lane = tid & 63, quad = lane >> 4, col = lane & 15;
  int m0 = blockIdx.x*64;           // 32 m-blocks
  int c  = blockIdx.y;              // 0..23
  int g  = c >> 1, kh = c & 1;

  {
    int srow = tid & 63;
    int grow = m0 + srow; if (grow > NPAIR-1) grow = NPAIR-1;
    int ah = (tid >> 6)*16;
    const __bf16* hp = hsb + (long long)grow*EMB + g*BLKsz + kh*32 + ah;
#pragma unroll
    for (int c0 = 0; c0 < 2; c0++) {
      bf16x8 hv = *(const bf16x8*)(hp + c0*8);
#pragma unroll
      for (int j = 0; j < 8; j++) hslT[ah + c0*8 + j][srow] = hv[j];
    }
  }
  bf16x8 tsv[2][2];
#pragma unroll
  for (int mf = 0; mf < 2; mf++) {
    int row = m0 + w*32 + mf*16 + col; if (row > NPAIR-1) row = NPAIR-1;
    const __bf16* tp = tsb + (long long)row*EMB + g*BLKsz + quad*8;
    tsv[mf][0] = *(const bf16x8*)(tp);
    tsv[mf][1] = *(const bf16x8*)(tp + 32);
  }
  __syncthreads();

  const __bf16* wg = wT + (long long)g*NL*4096 + kh*2048 + quad*8;
  int boff[7];
#pragma unroll
  for (int nt = 0; nt < 7; nt++) {
    int l = nt*16 + col; if (l > 96) l = 96;
    boff[nt] = l*4096;
  }
  f32x4 acc[2][7];
#pragma unroll
  for (int mf = 0; mf < 2; mf++)
#pragma unroll
    for (int nt = 0; nt < 7; nt++) acc[mf][nt] = (f32x4){0,0,0,0};

  bf16x8 bv[2][7];
#pragma unroll
  for (int nt = 0; nt < 7; nt++) bv[0][nt] = *(const bf16x8*)(wg + boff[nt]);
#pragma unroll
  for (int nt = 0; nt < 7; nt++) bv[1][nt] = *(const bf16x8*)(wg + boff[nt] + 32);

  for (int a = 0; a < 32; a++) {
    float hv[2];
#pragma unroll
    for (int mf = 0; mf < 2; mf++)
      hv[mf] = (float)hslT[a][w*32 + mf*16 + col];
#pragma unroll
    for (int half = 0; half < 2; half++) {
      bf16x8 af[2];
#pragma unroll
      for (int mf = 0; mf < 2; mf++)
#pragma unroll
        for (int j = 0; j < 8; j++)
          af[mf][j] = (__bf16)(hv[mf] * (float)tsv[mf][half][j]);
#pragma unroll
      for (int mf = 0; mf < 2; mf++)
#pragma unroll
        for (int nt = 0; nt < 7; nt++)
          acc[mf][nt] = __builtin_amdgcn_mfma_f32_16x16x32_bf16(af[mf], bv[half][nt],
                                                                acc[mf][nt], 0, 0, 0);
      int knext = (a+1)*64 + half*32;
      if (knext >= 2048) knext = a*64 + half*32;  // harmless refill at tail
#pragma unroll
      for (int nt = 0; nt < 7; nt++)
        bv[half][nt] = *(const bf16x8*)(wg + boff[nt] + knext);
    }
  }

  _Float16* ps = part24 + (long long)c*NPAIR*NL;
#pragma unroll
  for (int mf = 0; mf < 2; mf++)
#pragma unroll
    for (int nt = 0; nt < 7; nt++)
#pragma unroll
      for (int reg = 0; reg < 4; reg++) {
        int n = m0 + w*32 + mf*16 + quad*4 + reg;
        int l = nt*16 + col;
        if (n < NPAIR && l < NL)
          ps[(long long)n*NL + l] = (_Float16)acc[mf][nt][reg];
      }
}

// logits = sum_c part24 + b_bil; 4-wide.
__global__ void k_final(const _Float16* part24, const void* b_bil, const int* flag,
                        void* out) {
  int i4 = (blockIdx.x*256 + threadIdx.x)*4;
  if (i4 >= NPAIR*NL) return;
  int f32 = *flag;
  f32x4 v;
#pragma unroll
  for (int j = 0; j < 4; j++) v[j] = ldin(b_bil, (i4 + j) % NL, f32);
#pragma unroll
  for (int c = 0; c < NCHUNK; c++) {
    f16x4 pv = *(const f16x4*)(part24 + (long long)c*NPAIR*NL + i4);
#pragma unroll
    for (int j = 0; j < 4; j++) v[j] += (float)pv[j];
  }
  if (f32) {
    *(f32x4*)((float*)out + i4) = v;
  } else {
    bf16x4 ov;
#pragma unroll
    for (int j = 0; j < 4; j++) ov[j] = (__bf16)v[j];
    *(bf16x4*)((__hip_bfloat16*)out + i4) = ov;
  }
}

extern "C" void kernel_launch(void* const* d_in, const int* in_sizes, int n_in,
                              void* d_out, int out_size, void* d_ws, size_t ws_size,
                              hipStream_t stream) {
  const void* seq    = d_in[0];
  const void* att    = d_in[1];
  const int*  etok   = (const int*)d_in[2];
  const void* emask  = d_in[3];
  const int*  hts    = (const int*)d_in[4];
  const void* wliner = d_in[5];
  const void* bliner = d_in[6];
  const void* wseg   = d_in[7];
  const void* bseg   = d_in[8];
  const void* whead  = d_in[9];
  const void* bhead  = d_in[10];
  const void* wtail  = d_in[11];
  const void* btail  = d_in[12];
  const void* wbil   = d_in[13];
  const void* bbil   = d_in[14];

  char* ws = (char*)d_ws;
  int*      flag   = (int*)ws;
  float*    e_emb  = (float*)(ws + OFF_EEMB);
  __bf16*   e_att  = (__bf16*)(ws + OFF_EATT);
  float*    sp     = (float*)(ws + OFF_SP);
  __bf16*   Xb     = (__bf16*)(ws + OFF_XB);
  __bf16*   whT    = (__bf16*)(ws + OFF_WHT);
  __bf16*   wT     = (__bf16*)(ws + OFF_WT);
  __bf16*   hsb    = (__bf16*)(ws + OFF_HSB);
  __bf16*   tsb    = (__bf16*)(ws + OFF_TSB);
  _Float16* part24 = (_Float16*)(ws + OFF_PART);

  k_stage1<<<B_TOTAL, 256, 0, stream>>>(seq, att, etok, emask, wliner,
                                        whead, wtail, wbil, flag,
                                        e_emb, e_att, sp, whT, wT, Xb);
  k_pair<<<NPAIR, 256, 0, stream>>>(e_att, sp, e_emb, hts, bliner, wseg, bseg,
                                    flag, Xb);
  k_htmm<<<dim3(16, 12, 2), 256, 0, stream>>>(Xb, whT, bhead, btail, flag, hsb, tsb);
  k_bilmfma<<<dim3(32, NCHUNK), 128, 0, stream>>>(hsb, tsb, wT, part24);
  k_final<<<(NPAIR*NL/4 + 255)/256, 256, 0, stream>>>(part24, bbil, flag, d_out);
}